// Round 17
// baseline (64.426 us; speedup 1.0000x reference)
//
#include <hip/hip_runtime.h>
#include <hip/hip_bf16.h>

#define N      8192
#define D_IN   30
#define HID    32
#define D_OUT  30
#define FFD    128
#define ZC     34
#define JGC    16     // j-split groups

typedef __attribute__((ext_vector_type(8))) short short8;
typedef __attribute__((ext_vector_type(16))) float f32x16;

static __device__ __forceinline__ ushort f2bf(float x) {
    uint32_t u = __float_as_uint(x);
    uint32_t r = (u + 0x7fffu + ((u >> 16) & 1u)) >> 16;   // RTNE
    return (ushort)r;
}
static __device__ __forceinline__ float bf2f(ushort u) {
    return __uint_as_float(((uint32_t)u) << 16);
}
static __device__ __forceinline__ float rdlane(float v, int l) {
    return __uint_as_float(__builtin_amdgcn_readlane(__float_as_uint(v), l));
}

// ---------------------------------------------------------------------------
// Kernel A (R14-identical): QKV -> bf16; VWo^T (row30=0,row31=1 -> PV col31
// = rowsum); negated split-bf16 gate tables (gate MFMA = +D); W2e = W2@We,
// b2e = b2@We + be.
// ---------------------------------------------------------------------------
__global__ __launch_bounds__(256) void dv_qkv_kernel(
    const float* __restrict__ Z,
    const float* __restrict__ Wq, const float* __restrict__ bq,
    const float* __restrict__ Wk, const float* __restrict__ bk,
    const float* __restrict__ Wv, const float* __restrict__ bv,
    const float* __restrict__ Wo,
    const float* __restrict__ W2, const float* __restrict__ We,
    const float* __restrict__ b2, const float* __restrict__ be,
    ushort* __restrict__ Qb, ushort* __restrict__ Kb,
    ushort* __restrict__ VWot, ushort* __restrict__ KA,
    ushort* __restrict__ QB, float* __restrict__ W2e, float* __restrict__ b2e)
{
    __shared__ ushort sv[8][33];
    const int t = blockIdx.x * 256 + threadIdx.x;
    const int i = t >> 5;
    const int h = t & 31;
    const float* z = Z + (size_t)i * ZC;

    float q = bq[h], k = bk[h], v = bv[h];
#pragma unroll
    for (int d = 0; d < D_IN; ++d) {
        float zf = z[d];
        q = fmaf(zf, Wq[d * HID + h], q);
        k = fmaf(zf, Wk[d * HID + h], k);
        v = fmaf(zf, Wv[d * HID + h], v);
    }
    const float QS = 0.17677669529663687f * 1.4426950408889634f; // log2e/sqrt(32)
    Qb[(size_t)i * HID + h] = f2bf(q * QS);
    Kb[(size_t)i * HID + h] = f2bf(k);
    sv[threadIdx.x >> 5][h] = f2bf(v);

    if (h == 0) {
        float p0 = z[D_IN], p1 = z[D_IN + 1], p2 = z[D_IN + 2];
        const float C2 = 1.4426950408889634f / 0.18f;   // log2e/(2*sigma^2)
        const float SC = sqrtf(2.0f * C2);
        float px = p0 * SC, py = p1 * SC, pz = p2 * SC;
        float w  = -C2 * (p0 * p0 + p1 * p1 + p2 * p2);
        ushort phx = f2bf(px), phy = f2bf(py), phz = f2bf(pz);
        ushort plx = f2bf(px - bf2f(phx));
        ushort ply = f2bf(py - bf2f(phy));
        ushort plz = f2bf(pz - bf2f(phz));
        ushort wh  = f2bf(w);
        ushort wl  = f2bf(w - bf2f(wh));
        // negate j-side (KA) => MFMA result = +D
        ushort nhx = phx ^ 0x8000, nhy = phy ^ 0x8000, nhz = phz ^ 0x8000;
        ushort nlx = plx ^ 0x8000, nly = ply ^ 0x8000, nlz = plz ^ 0x8000;
        ushort nwh = wh ^ 0x8000,  nwl = wl ^ 0x8000;
        const ushort one = 0x3F80, none = 0xBF80;
        ushort ka0[8] = {nwh, nwl, none, none, nhx, nhy, nhz, nhx};
        ushort ka1[8] = {nhy, nhz, nlx, nly, nlz, nlx, nly, nlz};
        ushort qb0[8] = {one, one, wh, wl, phx, phy, phz, plx};
        ushort qb1[8] = {ply, plz, phx, phy, phz, plx, ply, plz};
        *(uint4*)&KA[(size_t)i * 8]       = *(uint4*)ka0;
        *(uint4*)&KA[((size_t)N + i) * 8] = *(uint4*)ka1;
        *(uint4*)&QB[(size_t)i * 8]       = *(uint4*)qb0;
        *(uint4*)&QB[((size_t)N + i) * 8] = *(uint4*)qb1;
    }

    // W2e = W2 @ We  (+ b2e) over the first 15 blocks
    if (blockIdx.x < 15) {
        int idx = blockIdx.x * 256 + threadIdx.x;      // 0..3839
        int f = idx / 30, o = idx - f * 30;
        float acc = 0.f;
#pragma unroll
        for (int d = 0; d < D_OUT; ++d)
            acc = fmaf(W2[f * D_OUT + d], We[d * D_OUT + o], acc);
        W2e[idx] = acc;
        if (idx < D_OUT) {
            float a2 = be[idx];
#pragma unroll
            for (int d = 0; d < D_OUT; ++d)
                a2 = fmaf(b2[d], We[d * D_OUT + idx], a2);
            b2e[idx] = a2;
        }
    }

    __syncthreads();
    // VWo^T: row c (0..29) = (V@Wo) col c; row 30 = 0; row 31 = 1.0
    const int io = threadIdx.x >> 5, c = threadIdx.x & 31;
    const int ii = blockIdx.x * 8 + io;
    float val;
    if (c < 30) {
        float acc = 0.f;
#pragma unroll
        for (int hh = 0; hh < HID; ++hh)
            acc = fmaf(bf2f(sv[io][hh]), Wo[hh * D_OUT + c], acc);
        val = acc;
    } else {
        val = (c == 31) ? 1.0f : 0.f;
    }
    VWot[(size_t)c * N + ii] = f2bf(val);
}

// ---------------------------------------------------------------------------
// Kernel B: barrier-light attention. V (the only uncoalesced-if-global
// operand) staged ONCE into 32KB LDS behind a single barrier; K and KA read
// global-direct per tile (L2-resident slabs). The 16-tile main loop has NO
// barriers -> deep load pipelining + independent wave progress.
// ---------------------------------------------------------------------------
__global__ __launch_bounds__(256) void dv_attn_kernel(
    const ushort* __restrict__ Qb, const ushort* __restrict__ Kb,
    const ushort* __restrict__ VWot, const ushort* __restrict__ KA,
    const ushort* __restrict__ QB, float* __restrict__ partial)
{
    __shared__ ushort lV[32 * 512];    // [o-dim][512 j], 8B-chunk XOR swizzle

    const int tid  = threadIdx.x;
    const int lane = tid & 63;
    const int wv   = tid >> 6;
    const int h2   = lane >> 5;
    const int l31  = lane & 31;
    const int rb   = blockIdx.x & 63;
    const int jg   = blockIdx.x >> 6;
    const int i0w  = rb * 128 + wv * 32;
    const int jgbase = jg << 9;        // jg * 512

    const ushort* qp = Qb + (size_t)(i0w + l31) * HID + h2 * 8;
    const short8 qf0 = *(const short8*)qp;
    const short8 qf1 = *(const short8*)(qp + 16);
    const short8 qaug = *(const short8*)&QB[((size_t)h2 * N + i0w + l31) * 8];

    // Stage the jg's full VWo^T slab: 32 rows x 512 j = 32KB (one barrier).
    // 8B unit (hh, cc) stored at chunk cc^hh within row hh.
#pragma unroll
    for (int rep = 0; rep < 16; ++rep) {
        int idx = tid + rep * 256;     // 0..4095
        int hh = idx >> 7;             // 0..31
        int cc = idx & 127;            // 8B-unit within row
        int cs = cc ^ hh;
        *(uint2*)&lV[hh * 512 + cs * 4] =
            *(const uint2*)&VWot[(size_t)hh * N + jgbase + cc * 4];
    }
    __syncthreads();                   // the ONLY barrier

    f32x16 zacc, oacc;
#pragma unroll
    for (int r = 0; r < 16; ++r) { zacc[r] = 0.f; oacc[r] = 0.f; }

    const ushort* vrow = &lV[l31 * 512];

    for (int ch = 0; ch < 4; ++ch) {
#pragma unroll
        for (int t32 = 0; t32 < 4; ++t32) {
            const int j0 = jgbase + ch * 128 + t32 * 32;
            // K fragments global-direct: chunks h2 and h2+2 of row j0+l31
            const ushort* krow = &Kb[(size_t)(j0 + l31) * HID + h2 * 8];
            short8 kf0 = *(const short8*)krow;
            short8 kf1 = *(const short8*)(krow + 16);
            // gate A-side global-direct (fully coalesced)
            short8 kaug = *(const short8*)&KA[((size_t)h2 * N + j0 + l31) * 8];

            f32x16 s = __builtin_amdgcn_mfma_f32_32x32x16_bf16(kf0, qf0, zacc, 0, 0, 0);
            s = __builtin_amdgcn_mfma_f32_32x32x16_bf16(kf1, qf1, s, 0, 0, 0);
            f32x16 gA = __builtin_amdgcn_mfma_f32_32x32x16_bf16(kaug, qaug, zacc, 0, 0, 0);

            uint32_t pk[8];
#pragma unroll
            for (int p = 0; p < 8; ++p) {
                // a = 2^-D * rcp(1 + 2^-S'); D >= -eps, all factors bounded
                float eg0 = __builtin_amdgcn_exp2f(-gA[2 * p]);
                float es0 = __builtin_amdgcn_exp2f(-s[2 * p]);
                float a0  = eg0 * __builtin_amdgcn_rcpf(1.0f + es0);
                float eg1 = __builtin_amdgcn_exp2f(-gA[2 * p + 1]);
                float es1 = __builtin_amdgcn_exp2f(-s[2 * p + 1]);
                float a1  = eg1 * __builtin_amdgcn_rcpf(1.0f + es1);
                asm("v_cvt_pk_bf16_f32 %0, %1, %2" : "=v"(pk[p]) : "v"(a0), "v"(a1));
            }
            union BV { uint32_t u[4]; short8 v; };
            BV fa, fb;
            fa.u[0] = pk[0]; fa.u[1] = pk[1]; fa.u[2] = pk[2]; fa.u[3] = pk[3];
            fb.u[0] = pk[4]; fb.u[1] = pk[5]; fb.u[2] = pk[6]; fb.u[3] = pk[7];

            // V fragments from LDS: logical 8B-chunk cb within the 512-j row
            const int cb = ch * 32 + t32 * 8 + h2;
            BV b0, b1;
            *(uint2*)&b0.u[0] = *(const uint2*)&vrow[((cb    ) ^ l31) * 4];
            *(uint2*)&b0.u[2] = *(const uint2*)&vrow[((cb + 2) ^ l31) * 4];
            *(uint2*)&b1.u[0] = *(const uint2*)&vrow[((cb + 4) ^ l31) * 4];
            *(uint2*)&b1.u[2] = *(const uint2*)&vrow[((cb + 6) ^ l31) * 4];

            oacc = __builtin_amdgcn_mfma_f32_32x32x16_bf16(fa.v, b0.v, oacc, 0, 0, 0);
            oacc = __builtin_amdgcn_mfma_f32_32x32x16_bf16(fb.v, b1.v, oacc, 0, 0, 0);
        }
    }

    // partial[i][jg*32 + c]: c<30 = raw pre-Wo H, c==31 = rowsum
#pragma unroll
    for (int r = 0; r < 16; ++r) {
        int ir = (r & 3) + 8 * (r >> 2) + 4 * h2 + i0w;
        partial[(size_t)ir * (JGC * 32) + jg * 32 + l31] = oacc[r];
    }
}

// ---------------------------------------------------------------------------
// Kernel C (R14-identical): epilogue v4 — wave-per-row, zero __syncthreads.
// ---------------------------------------------------------------------------
__global__ __launch_bounds__(256) void dv_epilogue_kernel(
    const float* __restrict__ partial,
    const float* __restrict__ bo,
    const float* __restrict__ ln_g, const float* __restrict__ ln_b,
    const float* __restrict__ W1, const float* __restrict__ b1,
    const float* __restrict__ W2e, const float* __restrict__ b2e,
    float* __restrict__ out)
{
    __shared__ float shf[4][FFD];    // per-wave private silu slice

    const int tid  = threadIdx.x;
    const int wv   = tid >> 6;
    const int lane = tid & 63;
    const int row  = blockIdx.x * 4 + wv;
    const int c    = lane & 31;
    const bool a30 = c < 30;
    const int  c30 = a30 ? c : 0;

    // P1: row's 512 partial floats; lane reads 8 (stride 64), fold lane^32.
    float s8 = 0.f;
    {
        const float* pp = partial + (size_t)row * (JGC * 32) + lane;
#pragma unroll
        for (int q = 0; q < 8; ++q) s8 += pp[q * 64];
    }
    float sv = s8 + __shfl_xor(s8, 32, 64);   // col sums, dup in both halves

    float rsum = __shfl(sv, 31, 32);          // col 31 = rowsum
    float inv  = __builtin_amdgcn_rcpf(rsum + 1e-8f);
    float Hl   = a30 ? fmaf(sv, inv, bo[c30]) : 0.f;

    // LayerNorm in-register (width-32; lanes with c>=30 contribute 0)
    float x = Hl;
#pragma unroll
    for (int m = 1; m < 32; m <<= 1) x += __shfl_xor(x, m, 32);
    float mu = x * (1.0f / D_OUT);
    float d  = a30 ? (Hl - mu) : 0.f;
    float v2 = d * d;
#pragma unroll
    for (int m = 1; m < 32; m <<= 1) v2 += __shfl_xor(v2, m, 32);
    float rs = rsqrtf(v2 * (1.0f / D_OUT) + 1e-5f);
    float Hn = fmaf(d * rs, ln_g[c30], ln_b[c30]);  // valid where a30

    // FFN1 + SiLU: lane owns f = lane and f = lane + 64 (coalesced W1 rows)
    float acc0 = b1[lane], acc1 = b1[lane + 64];
#pragma unroll
    for (int o = 0; o < D_OUT; ++o) {
        float ho = rdlane(Hn, o);             // lane o < 30 holds Hn[o]
        acc0 = fmaf(ho, W1[o * FFD + lane], acc0);
        acc1 = fmaf(ho, W1[o * FFD + lane + 64], acc1);
    }
    const float L2E = 1.4426950408889634f;
    shf[wv][lane] =
        acc0 * __builtin_amdgcn_rcpf(1.0f + __builtin_amdgcn_exp2f(-acc0 * L2E));
    shf[wv][lane + 64] =
        acc1 * __builtin_amdgcn_rcpf(1.0f + __builtin_amdgcn_exp2f(-acc1 * L2E));
    // same-wave ds_write -> ds_read: ordered by lgkmcnt, no barrier needed

    // FFN2e: half-wave h covers f in [h*64, h*64+64); o = c30 per lane.
    const int half = lane >> 5;
    float acc = 0.f;
    {
        const float* hbase = &shf[wv][half * 64];
#pragma unroll
        for (int k = 0; k < 16; ++k) {
            float4 hv = *(const float4*)&hbase[k * 4];
            const int f0 = half * 64 + k * 4;
            acc = fmaf(hv.x, W2e[(f0    ) * D_OUT + c30], acc);
            acc = fmaf(hv.y, W2e[(f0 + 1) * D_OUT + c30], acc);
            acc = fmaf(hv.z, W2e[(f0 + 2) * D_OUT + c30], acc);
            acc = fmaf(hv.w, W2e[(f0 + 3) * D_OUT + c30], acc);
        }
    }
    float val = acc + __shfl_xor(acc, 32, 64) + b2e[c30];

    if (lane < 32 && a30)
        out[(size_t)row * ZC + c] = val;

    float kep = a30 ? val * val : 0.f;
#pragma unroll
    for (int m = 1; m < 32; m <<= 1) kep += __shfl_xor(kep, m, 32);
    if (lane == 0) {
        float* op = out + (size_t)row * ZC;
        op[30] = 0.f; op[31] = 0.f; op[32] = 0.f;
        op[33] = kep * (0.5f / D_OUT);
    }
}

// ---------------------------------------------------------------------------
extern "C" void kernel_launch(void* const* d_in, const int* in_sizes, int n_in,
                              void* d_out, int out_size, void* d_ws, size_t ws_size,
                              hipStream_t stream)
{
    const float* Z  = (const float*)d_in[1];
    const float* Wq = (const float*)d_in[2];
    const float* bq = (const float*)d_in[3];
    const float* Wk = (const float*)d_in[4];
    const float* bk = (const float*)d_in[5];
    const float* Wv = (const float*)d_in[6];
    const float* bv = (const float*)d_in[7];
    const float* Wo = (const float*)d_in[8];
    const float* bo = (const float*)d_in[9];
    const float* lg = (const float*)d_in[10];
    const float* lb = (const float*)d_in[11];
    const float* W1 = (const float*)d_in[12];
    const float* b1 = (const float*)d_in[13];
    const float* W2 = (const float*)d_in[14];
    const float* b2 = (const float*)d_in[15];
    const float* We = (const float*)d_in[16];
    const float* be = (const float*)d_in[17];
    float* out = (float*)d_out;

    ushort* Qb   = (ushort*)d_ws;                 // N*32 bf16
    ushort* Kb   = Qb + (size_t)N * HID;          // N*32 bf16
    ushort* VWot = Kb + (size_t)N * HID;          // [32][N] bf16 (V@Wo)^T
    ushort* KA   = VWot + (size_t)N * HID;        // [2][N][8] bf16
    ushort* QB   = KA + (size_t)N * 16;           // [2][N][8] bf16
    float*  W2e  = (float*)(QB + (size_t)N * 16); // [128][30]
    float*  b2e  = W2e + FFD * D_OUT;             // [30] (+pad)
    float*  partial = b2e + 32;                   // [N][JGC*32] f32

    hipLaunchKernelGGL(dv_qkv_kernel, dim3((N * HID) / 256), dim3(256), 0, stream,
                       Z, Wq, bq, Wk, bk, Wv, bv, Wo, W2, We, b2, be,
                       Qb, Kb, VWot, KA, QB, W2e, b2e);
    hipLaunchKernelGGL(dv_attn_kernel, dim3(64 * JGC), dim3(256), 0, stream,
                       Qb, Kb, VWot, KA, QB, partial);
    hipLaunchKernelGGL(dv_epilogue_kernel, dim3(N / 4), dim3(256), 0, stream,
                       partial, bo, lg, lb, W1, b1, W2e, b2e, out);
}

// Round 18
// 59.209 us; speedup vs baseline: 1.0881x; 1.0881x over previous
//
#include <hip/hip_runtime.h>
#include <hip/hip_bf16.h>

#define N      8192
#define D_IN   30
#define HID    32
#define D_OUT  30
#define FFD    128
#define ZC     34
#define JGC    32     // j-split groups (bf16 partial keeps traffic = R14's)

typedef __attribute__((ext_vector_type(8))) short short8;
typedef __attribute__((ext_vector_type(16))) float f32x16;

static __device__ __forceinline__ ushort f2bf(float x) {
    uint32_t u = __float_as_uint(x);
    uint32_t r = (u + 0x7fffu + ((u >> 16) & 1u)) >> 16;   // RTNE
    return (ushort)r;
}
static __device__ __forceinline__ float bf2f(ushort u) {
    return __uint_as_float(((uint32_t)u) << 16);
}
static __device__ __forceinline__ float rdlane(float v, int l) {
    return __uint_as_float(__builtin_amdgcn_readlane(__float_as_uint(v), l));
}

// ---------------------------------------------------------------------------
// Kernel A (R14-identical): QKV -> bf16; VWo^T (row30=0,row31=1 -> PV col31
// = rowsum); negated split-bf16 gate tables (gate MFMA = +D); W2e = W2@We,
// b2e = b2@We + be.
// ---------------------------------------------------------------------------
__global__ __launch_bounds__(256) void dv_qkv_kernel(
    const float* __restrict__ Z,
    const float* __restrict__ Wq, const float* __restrict__ bq,
    const float* __restrict__ Wk, const float* __restrict__ bk,
    const float* __restrict__ Wv, const float* __restrict__ bv,
    const float* __restrict__ Wo,
    const float* __restrict__ W2, const float* __restrict__ We,
    const float* __restrict__ b2, const float* __restrict__ be,
    ushort* __restrict__ Qb, ushort* __restrict__ Kb,
    ushort* __restrict__ VWot, ushort* __restrict__ KA,
    ushort* __restrict__ QB, float* __restrict__ W2e, float* __restrict__ b2e)
{
    __shared__ ushort sv[8][33];
    const int t = blockIdx.x * 256 + threadIdx.x;
    const int i = t >> 5;
    const int h = t & 31;
    const float* z = Z + (size_t)i * ZC;

    float q = bq[h], k = bk[h], v = bv[h];
#pragma unroll
    for (int d = 0; d < D_IN; ++d) {
        float zf = z[d];
        q = fmaf(zf, Wq[d * HID + h], q);
        k = fmaf(zf, Wk[d * HID + h], k);
        v = fmaf(zf, Wv[d * HID + h], v);
    }
    const float QS = 0.17677669529663687f * 1.4426950408889634f; // log2e/sqrt(32)
    Qb[(size_t)i * HID + h] = f2bf(q * QS);
    Kb[(size_t)i * HID + h] = f2bf(k);
    sv[threadIdx.x >> 5][h] = f2bf(v);

    if (h == 0) {
        float p0 = z[D_IN], p1 = z[D_IN + 1], p2 = z[D_IN + 2];
        const float C2 = 1.4426950408889634f / 0.18f;   // log2e/(2*sigma^2)
        const float SC = sqrtf(2.0f * C2);
        float px = p0 * SC, py = p1 * SC, pz = p2 * SC;
        float w  = -C2 * (p0 * p0 + p1 * p1 + p2 * p2);
        ushort phx = f2bf(px), phy = f2bf(py), phz = f2bf(pz);
        ushort plx = f2bf(px - bf2f(phx));
        ushort ply = f2bf(py - bf2f(phy));
        ushort plz = f2bf(pz - bf2f(phz));
        ushort wh  = f2bf(w);
        ushort wl  = f2bf(w - bf2f(wh));
        // negate j-side (KA) => MFMA result = +D
        ushort nhx = phx ^ 0x8000, nhy = phy ^ 0x8000, nhz = phz ^ 0x8000;
        ushort nlx = plx ^ 0x8000, nly = ply ^ 0x8000, nlz = plz ^ 0x8000;
        ushort nwh = wh ^ 0x8000,  nwl = wl ^ 0x8000;
        const ushort one = 0x3F80, none = 0xBF80;
        ushort ka0[8] = {nwh, nwl, none, none, nhx, nhy, nhz, nhx};
        ushort ka1[8] = {nhy, nhz, nlx, nly, nlz, nlx, nly, nlz};
        ushort qb0[8] = {one, one, wh, wl, phx, phy, phz, plx};
        ushort qb1[8] = {ply, plz, phx, phy, phz, plx, ply, plz};
        *(uint4*)&KA[(size_t)i * 8]       = *(uint4*)ka0;
        *(uint4*)&KA[((size_t)N + i) * 8] = *(uint4*)ka1;
        *(uint4*)&QB[(size_t)i * 8]       = *(uint4*)qb0;
        *(uint4*)&QB[((size_t)N + i) * 8] = *(uint4*)qb1;
    }

    // W2e = W2 @ We  (+ b2e) over the first 15 blocks
    if (blockIdx.x < 15) {
        int idx = blockIdx.x * 256 + threadIdx.x;      // 0..3839
        int f = idx / 30, o = idx - f * 30;
        float acc = 0.f;
#pragma unroll
        for (int d = 0; d < D_OUT; ++d)
            acc = fmaf(W2[f * D_OUT + d], We[d * D_OUT + o], acc);
        W2e[idx] = acc;
        if (idx < D_OUT) {
            float a2 = be[idx];
#pragma unroll
            for (int d = 0; d < D_OUT; ++d)
                a2 = fmaf(b2[d], We[d * D_OUT + idx], a2);
            b2e[idx] = a2;
        }
    }

    __syncthreads();
    // VWo^T: row c (0..29) = (V@Wo) col c; row 30 = 0; row 31 = 1.0
    const int io = threadIdx.x >> 5, c = threadIdx.x & 31;
    const int ii = blockIdx.x * 8 + io;
    float val;
    if (c < 30) {
        float acc = 0.f;
#pragma unroll
        for (int hh = 0; hh < HID; ++hh)
            acc = fmaf(bf2f(sv[io][hh]), Wo[hh * D_OUT + c], acc);
        val = acc;
    } else {
        val = (c == 31) ? 1.0f : 0.f;
    }
    VWot[(size_t)c * N + ii] = f2bf(val);
}

// ---------------------------------------------------------------------------
// Kernel B: R14 attention (LDS staging, reg prefetch, bounded gate), JGC=32
// (nch=2, 2048 blocks -> ~2x blocks/CU), bf16 partial output (traffic = R14).
// ---------------------------------------------------------------------------
__global__ __launch_bounds__(256, 2) void dv_attn_kernel(
    const ushort* __restrict__ Qb, const ushort* __restrict__ Kb,
    const ushort* __restrict__ VWot, const ushort* __restrict__ KA,
    const ushort* __restrict__ QB, ushort* __restrict__ partial, int nch)
{
    __shared__ ushort lK[128 * 32];    // K tile, 16B-chunk rot swizzle
    __shared__ ushort lV[32 * 128];    // VWo^T tile, 8B-chunk XOR swizzle
    __shared__ ushort lKA[2][128 * 8]; // gate A-side aug

    const int tid  = threadIdx.x;
    const int lane = tid & 63;
    const int wv   = tid >> 6;
    const int h2   = lane >> 5;
    const int l31  = lane & 31;
    const int rb   = blockIdx.x & 63;
    const int jg   = blockIdx.x >> 6;
    const int i0w  = rb * 128 + wv * 32;

    const ushort* qp = Qb + (size_t)(i0w + l31) * HID + h2 * 8;
    const short8 qf0 = *(const short8*)qp;
    const short8 qf1 = *(const short8*)(qp + 16);
    const short8 qaug = *(const short8*)&QB[((size_t)h2 * N + i0w + l31) * 8];

    f32x16 zacc, oacc;
#pragma unroll
    for (int r = 0; r < 16; ++r) { zacc[r] = 0.f; oacc[r] = 0.f; }

    const int cA0 = (h2 + (l31 >> 1)) & 3;
    const int cA1 = (cA0 + 2) & 3;

    // staging indices (fixed per thread)
    const int kjr0 = tid >> 2,          kcc0 = tid & 3;
    const int kjr1 = (tid + 256) >> 2,  kcc1 = (tid + 256) & 3;
    const int kc20 = (kcc0 + (kjr0 >> 1)) & 3;
    const int kc21 = (kcc1 + (kjr1 >> 1)) & 3;
    const int vhh[4] = { tid >> 5, (tid + 256) >> 5, (tid + 512) >> 5, (tid + 768) >> 5 };
    const int vcx = tid & 31;
    const int ahalf = tid >> 7, ajj = tid & 127;

    uint4 kreg[2];
    uint2 vreg[4];
    uint4 kareg;

    // prologue: load chunk 0
    {
        const int j0 = (jg * nch) << 7;
        kreg[0] = *(const uint4*)&Kb[(size_t)(j0 + kjr0) * HID + kcc0 * 8];
        kreg[1] = *(const uint4*)&Kb[(size_t)(j0 + kjr1) * HID + kcc1 * 8];
#pragma unroll
        for (int r2 = 0; r2 < 4; ++r2)
            vreg[r2] = *(const uint2*)&VWot[(size_t)vhh[r2] * N + j0 + vcx * 4];
        kareg = *(const uint4*)&KA[((size_t)ahalf * N + j0 + ajj) * 8];
    }

    for (int ch = 0; ch < nch; ++ch) {
        __syncthreads();   // previous compute done; LDS free
        *(uint4*)&lK[kjr0 * 32 + kc20 * 8] = kreg[0];
        *(uint4*)&lK[kjr1 * 32 + kc21 * 8] = kreg[1];
#pragma unroll
        for (int r2 = 0; r2 < 4; ++r2)
            *(uint2*)&lV[vhh[r2] * 128 + (vcx ^ vhh[r2]) * 4] = vreg[r2];
        *(uint4*)&lKA[ahalf][ajj * 8] = kareg;
        __syncthreads();   // LDS ready

        // issue next chunk's global loads (land under this chunk's compute)
        if (ch + 1 < nch) {
            const int j1 = (jg * nch + ch + 1) << 7;
            kreg[0] = *(const uint4*)&Kb[(size_t)(j1 + kjr0) * HID + kcc0 * 8];
            kreg[1] = *(const uint4*)&Kb[(size_t)(j1 + kjr1) * HID + kcc1 * 8];
#pragma unroll
            for (int r2 = 0; r2 < 4; ++r2)
                vreg[r2] = *(const uint2*)&VWot[(size_t)vhh[r2] * N + j1 + vcx * 4];
            kareg = *(const uint4*)&KA[((size_t)ahalf * N + j1 + ajj) * 8];
        }

#pragma unroll
        for (int t32 = 0; t32 < 4; ++t32) {
            const ushort* krow = &lK[(t32 * 32 + l31) * 32];
            short8 kf0 = *(const short8*)&krow[cA0 * 8];
            short8 kf1 = *(const short8*)&krow[cA1 * 8];
            f32x16 s = __builtin_amdgcn_mfma_f32_32x32x16_bf16(kf0, qf0, zacc, 0, 0, 0);
            s = __builtin_amdgcn_mfma_f32_32x32x16_bf16(kf1, qf1, s, 0, 0, 0);

            short8 kaug = *(const short8*)&lKA[h2][(t32 * 32 + l31) * 8];
            f32x16 gA = __builtin_amdgcn_mfma_f32_32x32x16_bf16(kaug, qaug, zacc, 0, 0, 0);

            uint32_t pk[8];
#pragma unroll
            for (int p = 0; p < 8; ++p) {
                // a = 2^-D * rcp(1 + 2^-S'); D >= -eps, all factors bounded
                float eg0 = __builtin_amdgcn_exp2f(-gA[2 * p]);
                float es0 = __builtin_amdgcn_exp2f(-s[2 * p]);
                float a0  = eg0 * __builtin_amdgcn_rcpf(1.0f + es0);
                float eg1 = __builtin_amdgcn_exp2f(-gA[2 * p + 1]);
                float es1 = __builtin_amdgcn_exp2f(-s[2 * p + 1]);
                float a1  = eg1 * __builtin_amdgcn_rcpf(1.0f + es1);
                asm("v_cvt_pk_bf16_f32 %0, %1, %2" : "=v"(pk[p]) : "v"(a0), "v"(a1));
            }
            union BV { uint32_t u[4]; short8 v; };
            BV fa, fb;
            fa.u[0] = pk[0]; fa.u[1] = pk[1]; fa.u[2] = pk[2]; fa.u[3] = pk[3];
            fb.u[0] = pk[4]; fb.u[1] = pk[5]; fb.u[2] = pk[6]; fb.u[3] = pk[7];

            const ushort* vrow = &lV[l31 * 128];
            const int cb = t32 * 8 + h2;
            BV b0, b1;
            *(uint2*)&b0.u[0] = *(const uint2*)&vrow[((cb    ) ^ l31) * 4];
            *(uint2*)&b0.u[2] = *(const uint2*)&vrow[((cb + 2) ^ l31) * 4];
            *(uint2*)&b1.u[0] = *(const uint2*)&vrow[((cb + 4) ^ l31) * 4];
            *(uint2*)&b1.u[2] = *(const uint2*)&vrow[((cb + 6) ^ l31) * 4];

            oacc = __builtin_amdgcn_mfma_f32_32x32x16_bf16(fa.v, b0.v, oacc, 0, 0, 0);
            oacc = __builtin_amdgcn_mfma_f32_32x32x16_bf16(fb.v, b1.v, oacc, 0, 0, 0);
        }
    }

    // partial[i][jg*32 + c] (bf16): c<30 = raw pre-Wo H, c==31 = rowsum
#pragma unroll
    for (int r = 0; r < 16; ++r) {
        int ir = (r & 3) + 8 * (r >> 2) + 4 * h2 + i0w;
        partial[(size_t)ir * (JGC * 32) + jg * 32 + l31] = f2bf(oacc[r]);
    }
}

// ---------------------------------------------------------------------------
// Kernel C: epilogue v4 (wave-per-row, zero __syncthreads), bf16 partial in.
// P1: lane c = lane&31, half = lane>>5 sums jg = half*16..+15, fold ^32.
// ---------------------------------------------------------------------------
__global__ __launch_bounds__(256) void dv_epilogue_kernel(
    const ushort* __restrict__ partial,
    const float* __restrict__ bo,
    const float* __restrict__ ln_g, const float* __restrict__ ln_b,
    const float* __restrict__ W1, const float* __restrict__ b1,
    const float* __restrict__ W2e, const float* __restrict__ b2e,
    float* __restrict__ out)
{
    __shared__ float shf[4][FFD];    // per-wave private silu slice

    const int tid  = threadIdx.x;
    const int wv   = tid >> 6;
    const int lane = tid & 63;
    const int row  = blockIdx.x * 4 + wv;
    const int c    = lane & 31;
    const int half = lane >> 5;
    const bool a30 = c < 30;
    const int  c30 = a30 ? c : 0;

    // P1: sum 16 of 32 jg entries for col c (half-wave split), fold ^32.
    float s8 = 0.f;
    {
        const ushort* pp = partial + (size_t)row * (JGC * 32) + half * 16 * 32 + c;
#pragma unroll
        for (int q = 0; q < 16; ++q) s8 += bf2f(pp[q * 32]);
    }
    float sv = s8 + __shfl_xor(s8, 32, 64);   // col sums, dup in both halves

    float rsum = __shfl(sv, 31, 32);          // col 31 = rowsum
    float inv  = __builtin_amdgcn_rcpf(rsum + 1e-8f);
    float Hl   = a30 ? fmaf(sv, inv, bo[c30]) : 0.f;

    // LayerNorm in-register (width-32; lanes with c>=30 contribute 0)
    float x = Hl;
#pragma unroll
    for (int m = 1; m < 32; m <<= 1) x += __shfl_xor(x, m, 32);
    float mu = x * (1.0f / D_OUT);
    float d  = a30 ? (Hl - mu) : 0.f;
    float v2 = d * d;
#pragma unroll
    for (int m = 1; m < 32; m <<= 1) v2 += __shfl_xor(v2, m, 32);
    float rs = rsqrtf(v2 * (1.0f / D_OUT) + 1e-5f);
    float Hn = fmaf(d * rs, ln_g[c30], ln_b[c30]);  // valid where a30

    // FFN1 + SiLU: lane owns f = lane and f = lane + 64 (coalesced W1 rows)
    float acc0 = b1[lane], acc1 = b1[lane + 64];
#pragma unroll
    for (int o = 0; o < D_OUT; ++o) {
        float ho = rdlane(Hn, o);             // lane o < 30 holds Hn[o]
        acc0 = fmaf(ho, W1[o * FFD + lane], acc0);
        acc1 = fmaf(ho, W1[o * FFD + lane + 64], acc1);
    }
    const float L2E = 1.4426950408889634f;
    shf[wv][lane] =
        acc0 * __builtin_amdgcn_rcpf(1.0f + __builtin_amdgcn_exp2f(-acc0 * L2E));
    shf[wv][lane + 64] =
        acc1 * __builtin_amdgcn_rcpf(1.0f + __builtin_amdgcn_exp2f(-acc1 * L2E));
    // same-wave ds_write -> ds_read: ordered by lgkmcnt, no barrier needed

    // FFN2e: half-wave h covers f in [h*64, h*64+64); o = c30 per lane.
    float acc = 0.f;
    {
        const float* hbase = &shf[wv][half * 64];
#pragma unroll
        for (int k = 0; k < 16; ++k) {
            float4 hv = *(const float4*)&hbase[k * 4];
            const int f0 = half * 64 + k * 4;
            acc = fmaf(hv.x, W2e[(f0    ) * D_OUT + c30], acc);
            acc = fmaf(hv.y, W2e[(f0 + 1) * D_OUT + c30], acc);
            acc = fmaf(hv.z, W2e[(f0 + 2) * D_OUT + c30], acc);
            acc = fmaf(hv.w, W2e[(f0 + 3) * D_OUT + c30], acc);
        }
    }
    float val = acc + __shfl_xor(acc, 32, 64) + b2e[c30];

    if (lane < 32 && a30)
        out[(size_t)row * ZC + c] = val;

    float kep = (a30 && half == 0) ? val * val : 0.f;
#pragma unroll
    for (int m = 1; m < 32; m <<= 1) kep += __shfl_xor(kep, m, 32);
    if (lane == 0) {
        float* op = out + (size_t)row * ZC;
        op[30] = 0.f; op[31] = 0.f; op[32] = 0.f;
        op[33] = kep * (0.5f / D_OUT);
    }
}

// ---------------------------------------------------------------------------
extern "C" void kernel_launch(void* const* d_in, const int* in_sizes, int n_in,
                              void* d_out, int out_size, void* d_ws, size_t ws_size,
                              hipStream_t stream)
{
    const float* Z  = (const float*)d_in[1];
    const float* Wq = (const float*)d_in[2];
    const float* bq = (const float*)d_in[3];
    const float* Wk = (const float*)d_in[4];
    const float* bk = (const float*)d_in[5];
    const float* Wv = (const float*)d_in[6];
    const float* bv = (const float*)d_in[7];
    const float* Wo = (const float*)d_in[8];
    const float* bo = (const float*)d_in[9];
    const float* lg = (const float*)d_in[10];
    const float* lb = (const float*)d_in[11];
    const float* W1 = (const float*)d_in[12];
    const float* b1 = (const float*)d_in[13];
    const float* W2 = (const float*)d_in[14];
    const float* b2 = (const float*)d_in[15];
    const float* We = (const float*)d_in[16];
    const float* be = (const float*)d_in[17];
    float* out = (float*)d_out;

    ushort* Qb   = (ushort*)d_ws;                 // N*32 bf16
    ushort* Kb   = Qb + (size_t)N * HID;          // N*32 bf16
    ushort* VWot = Kb + (size_t)N * HID;          // [32][N] bf16 (V@Wo)^T
    ushort* KA   = VWot + (size_t)N * HID;        // [2][N][8] bf16
    ushort* QB   = KA + (size_t)N * 16;           // [2][N][8] bf16
    float*  W2e  = (float*)(QB + (size_t)N * 16); // [128][30]
    float*  b2e  = W2e + FFD * D_OUT;             // [30] (+pad)
    ushort* partial = (ushort*)(b2e + 32);        // [N][JGC*32] bf16

    int nch = N / (JGC * 128);

    hipLaunchKernelGGL(dv_qkv_kernel, dim3((N * HID) / 256), dim3(256), 0, stream,
                       Z, Wq, bq, Wk, bk, Wv, bv, Wo, W2, We, b2, be,
                       Qb, Kb, VWot, KA, QB, W2e, b2e);
    hipLaunchKernelGGL(dv_attn_kernel, dim3(64 * JGC), dim3(256), 0, stream,
                       Qb, Kb, VWot, KA, QB, partial, nch);
    hipLaunchKernelGGL(dv_epilogue_kernel, dim3(N / 4), dim3(256), 0, stream,
                       partial, bo, lg, lb, W1, b1, W2e, b2e, out);
}

// Round 19
// 56.668 us; speedup vs baseline: 1.1369x; 1.0448x over previous
//
#include <hip/hip_runtime.h>
#include <hip/hip_bf16.h>

#define N      8192
#define D_IN   30
#define HID    32
#define D_OUT  30
#define FFD    128
#define ZC     34
#define JGC    16     // j-split groups

typedef __attribute__((ext_vector_type(8))) short short8;
typedef __attribute__((ext_vector_type(16))) float f32x16;

static __device__ __forceinline__ ushort f2bf(float x) {
    uint32_t u = __float_as_uint(x);
    uint32_t r = (u + 0x7fffu + ((u >> 16) & 1u)) >> 16;   // RTNE
    return (ushort)r;
}
static __device__ __forceinline__ float bf2f(ushort u) {
    return __uint_as_float(((uint32_t)u) << 16);
}
static __device__ __forceinline__ float rdlane(float v, int l) {
    return __uint_as_float(__builtin_amdgcn_readlane(__float_as_uint(v), l));
}

// ---------------------------------------------------------------------------
// Kernel A (R14-identical): QKV -> bf16; VWo^T (row30=0,row31=1 -> PV col31
// = rowsum); negated split-bf16 gate tables (gate MFMA = +D); W2e = W2@We,
// b2e = b2@We + be.
// ---------------------------------------------------------------------------
__global__ __launch_bounds__(256) void dv_qkv_kernel(
    const float* __restrict__ Z,
    const float* __restrict__ Wq, const float* __restrict__ bq,
    const float* __restrict__ Wk, const float* __restrict__ bk,
    const float* __restrict__ Wv, const float* __restrict__ bv,
    const float* __restrict__ Wo,
    const float* __restrict__ W2, const float* __restrict__ We,
    const float* __restrict__ b2, const float* __restrict__ be,
    ushort* __restrict__ Qb, ushort* __restrict__ Kb,
    ushort* __restrict__ VWot, ushort* __restrict__ KA,
    ushort* __restrict__ QB, float* __restrict__ W2e, float* __restrict__ b2e)
{
    __shared__ ushort sv[8][33];
    const int t = blockIdx.x * 256 + threadIdx.x;
    const int i = t >> 5;
    const int h = t & 31;
    const float* z = Z + (size_t)i * ZC;

    float q = bq[h], k = bk[h], v = bv[h];
#pragma unroll
    for (int d = 0; d < D_IN; ++d) {
        float zf = z[d];
        q = fmaf(zf, Wq[d * HID + h], q);
        k = fmaf(zf, Wk[d * HID + h], k);
        v = fmaf(zf, Wv[d * HID + h], v);
    }
    const float QS = 0.17677669529663687f * 1.4426950408889634f; // log2e/sqrt(32)
    Qb[(size_t)i * HID + h] = f2bf(q * QS);
    Kb[(size_t)i * HID + h] = f2bf(k);
    sv[threadIdx.x >> 5][h] = f2bf(v);

    if (h == 0) {
        float p0 = z[D_IN], p1 = z[D_IN + 1], p2 = z[D_IN + 2];
        const float C2 = 1.4426950408889634f / 0.18f;   // log2e/(2*sigma^2)
        const float SC = sqrtf(2.0f * C2);
        float px = p0 * SC, py = p1 * SC, pz = p2 * SC;
        float w  = -C2 * (p0 * p0 + p1 * p1 + p2 * p2);
        ushort phx = f2bf(px), phy = f2bf(py), phz = f2bf(pz);
        ushort plx = f2bf(px - bf2f(phx));
        ushort ply = f2bf(py - bf2f(phy));
        ushort plz = f2bf(pz - bf2f(phz));
        ushort wh  = f2bf(w);
        ushort wl  = f2bf(w - bf2f(wh));
        // negate j-side (KA) => MFMA result = +D
        ushort nhx = phx ^ 0x8000, nhy = phy ^ 0x8000, nhz = phz ^ 0x8000;
        ushort nlx = plx ^ 0x8000, nly = ply ^ 0x8000, nlz = plz ^ 0x8000;
        ushort nwh = wh ^ 0x8000,  nwl = wl ^ 0x8000;
        const ushort one = 0x3F80, none = 0xBF80;
        ushort ka0[8] = {nwh, nwl, none, none, nhx, nhy, nhz, nhx};
        ushort ka1[8] = {nhy, nhz, nlx, nly, nlz, nlx, nly, nlz};
        ushort qb0[8] = {one, one, wh, wl, phx, phy, phz, plx};
        ushort qb1[8] = {ply, plz, phx, phy, phz, plx, ply, plz};
        *(uint4*)&KA[(size_t)i * 8]       = *(uint4*)ka0;
        *(uint4*)&KA[((size_t)N + i) * 8] = *(uint4*)ka1;
        *(uint4*)&QB[(size_t)i * 8]       = *(uint4*)qb0;
        *(uint4*)&QB[((size_t)N + i) * 8] = *(uint4*)qb1;
    }

    // W2e = W2 @ We  (+ b2e) over the first 15 blocks
    if (blockIdx.x < 15) {
        int idx = blockIdx.x * 256 + threadIdx.x;      // 0..3839
        int f = idx / 30, o = idx - f * 30;
        float acc = 0.f;
#pragma unroll
        for (int d = 0; d < D_OUT; ++d)
            acc = fmaf(W2[f * D_OUT + d], We[d * D_OUT + o], acc);
        W2e[idx] = acc;
        if (idx < D_OUT) {
            float a2 = be[idx];
#pragma unroll
            for (int d = 0; d < D_OUT; ++d)
                a2 = fmaf(b2[d], We[d * D_OUT + idx], a2);
            b2e[idx] = a2;
        }
    }

    __syncthreads();
    // VWo^T: row c (0..29) = (V@Wo) col c; row 30 = 0; row 31 = 1.0
    const int io = threadIdx.x >> 5, c = threadIdx.x & 31;
    const int ii = blockIdx.x * 8 + io;
    float val;
    if (c < 30) {
        float acc = 0.f;
#pragma unroll
        for (int hh = 0; hh < HID; ++hh)
            acc = fmaf(bf2f(sv[io][hh]), Wo[hh * D_OUT + c], acc);
        val = acc;
    } else {
        val = (c == 31) ? 1.0f : 0.f;
    }
    VWot[(size_t)c * N + ii] = f2bf(val);
}

// ---------------------------------------------------------------------------
// Kernel B: R14 attention (LDS staging, reg prefetch, bounded gate) with
// bf16 partial output (halves partial traffic; accuracy proven in R18) and
// T5 s_setprio(1) around the per-chunk compute region (4 independent
// blocks/CU at different phases -> scheduler role diversity).
// ---------------------------------------------------------------------------
__global__ __launch_bounds__(256, 2) void dv_attn_kernel(
    const ushort* __restrict__ Qb, const ushort* __restrict__ Kb,
    const ushort* __restrict__ VWot, const ushort* __restrict__ KA,
    const ushort* __restrict__ QB, ushort* __restrict__ partial, int nch)
{
    __shared__ ushort lK[128 * 32];    // K tile, 16B-chunk rot swizzle
    __shared__ ushort lV[32 * 128];    // VWo^T tile, 8B-chunk XOR swizzle
    __shared__ ushort lKA[2][128 * 8]; // gate A-side aug

    const int tid  = threadIdx.x;
    const int lane = tid & 63;
    const int wv   = tid >> 6;
    const int h2   = lane >> 5;
    const int l31  = lane & 31;
    const int rb   = blockIdx.x & 63;
    const int jg   = blockIdx.x >> 6;
    const int i0w  = rb * 128 + wv * 32;

    const ushort* qp = Qb + (size_t)(i0w + l31) * HID + h2 * 8;
    const short8 qf0 = *(const short8*)qp;
    const short8 qf1 = *(const short8*)(qp + 16);
    const short8 qaug = *(const short8*)&QB[((size_t)h2 * N + i0w + l31) * 8];

    f32x16 zacc, oacc;
#pragma unroll
    for (int r = 0; r < 16; ++r) { zacc[r] = 0.f; oacc[r] = 0.f; }

    const int cA0 = (h2 + (l31 >> 1)) & 3;
    const int cA1 = (cA0 + 2) & 3;

    // staging indices (fixed per thread)
    const int kjr0 = tid >> 2,          kcc0 = tid & 3;
    const int kjr1 = (tid + 256) >> 2,  kcc1 = (tid + 256) & 3;
    const int kc20 = (kcc0 + (kjr0 >> 1)) & 3;
    const int kc21 = (kcc1 + (kjr1 >> 1)) & 3;
    const int vhh[4] = { tid >> 5, (tid + 256) >> 5, (tid + 512) >> 5, (tid + 768) >> 5 };
    const int vcx = tid & 31;
    const int ahalf = tid >> 7, ajj = tid & 127;

    uint4 kreg[2];
    uint2 vreg[4];
    uint4 kareg;

    // prologue: load chunk 0
    {
        const int j0 = (jg * nch) << 7;
        kreg[0] = *(const uint4*)&Kb[(size_t)(j0 + kjr0) * HID + kcc0 * 8];
        kreg[1] = *(const uint4*)&Kb[(size_t)(j0 + kjr1) * HID + kcc1 * 8];
#pragma unroll
        for (int r2 = 0; r2 < 4; ++r2)
            vreg[r2] = *(const uint2*)&VWot[(size_t)vhh[r2] * N + j0 + vcx * 4];
        kareg = *(const uint4*)&KA[((size_t)ahalf * N + j0 + ajj) * 8];
    }

    for (int ch = 0; ch < nch; ++ch) {
        __syncthreads();   // previous compute done; LDS free
        *(uint4*)&lK[kjr0 * 32 + kc20 * 8] = kreg[0];
        *(uint4*)&lK[kjr1 * 32 + kc21 * 8] = kreg[1];
#pragma unroll
        for (int r2 = 0; r2 < 4; ++r2)
            *(uint2*)&lV[vhh[r2] * 128 + (vcx ^ vhh[r2]) * 4] = vreg[r2];
        *(uint4*)&lKA[ahalf][ajj * 8] = kareg;
        __syncthreads();   // LDS ready

        // issue next chunk's global loads (land under this chunk's compute)
        if (ch + 1 < nch) {
            const int j1 = (jg * nch + ch + 1) << 7;
            kreg[0] = *(const uint4*)&Kb[(size_t)(j1 + kjr0) * HID + kcc0 * 8];
            kreg[1] = *(const uint4*)&Kb[(size_t)(j1 + kjr1) * HID + kcc1 * 8];
#pragma unroll
            for (int r2 = 0; r2 < 4; ++r2)
                vreg[r2] = *(const uint2*)&VWot[(size_t)vhh[r2] * N + j1 + vcx * 4];
            kareg = *(const uint4*)&KA[((size_t)ahalf * N + j1 + ajj) * 8];
        }

        __builtin_amdgcn_s_setprio(1);
#pragma unroll
        for (int t32 = 0; t32 < 4; ++t32) {
            const ushort* krow = &lK[(t32 * 32 + l31) * 32];
            short8 kf0 = *(const short8*)&krow[cA0 * 8];
            short8 kf1 = *(const short8*)&krow[cA1 * 8];
            f32x16 s = __builtin_amdgcn_mfma_f32_32x32x16_bf16(kf0, qf0, zacc, 0, 0, 0);
            s = __builtin_amdgcn_mfma_f32_32x32x16_bf16(kf1, qf1, s, 0, 0, 0);

            short8 kaug = *(const short8*)&lKA[h2][(t32 * 32 + l31) * 8];
            f32x16 gA = __builtin_amdgcn_mfma_f32_32x32x16_bf16(kaug, qaug, zacc, 0, 0, 0);

            uint32_t pk[8];
#pragma unroll
            for (int p = 0; p < 8; ++p) {
                // a = 2^-D * rcp(1 + 2^-S'); D >= -eps, all factors bounded
                float eg0 = __builtin_amdgcn_exp2f(-gA[2 * p]);
                float es0 = __builtin_amdgcn_exp2f(-s[2 * p]);
                float a0  = eg0 * __builtin_amdgcn_rcpf(1.0f + es0);
                float eg1 = __builtin_amdgcn_exp2f(-gA[2 * p + 1]);
                float es1 = __builtin_amdgcn_exp2f(-s[2 * p + 1]);
                float a1  = eg1 * __builtin_amdgcn_rcpf(1.0f + es1);
                asm("v_cvt_pk_bf16_f32 %0, %1, %2" : "=v"(pk[p]) : "v"(a0), "v"(a1));
            }
            union BV { uint32_t u[4]; short8 v; };
            BV fa, fb;
            fa.u[0] = pk[0]; fa.u[1] = pk[1]; fa.u[2] = pk[2]; fa.u[3] = pk[3];
            fb.u[0] = pk[4]; fb.u[1] = pk[5]; fb.u[2] = pk[6]; fb.u[3] = pk[7];

            const ushort* vrow = &lV[l31 * 128];
            const int cb = t32 * 8 + h2;
            BV b0, b1;
            *(uint2*)&b0.u[0] = *(const uint2*)&vrow[((cb    ) ^ l31) * 4];
            *(uint2*)&b0.u[2] = *(const uint2*)&vrow[((cb + 2) ^ l31) * 4];
            *(uint2*)&b1.u[0] = *(const uint2*)&vrow[((cb + 4) ^ l31) * 4];
            *(uint2*)&b1.u[2] = *(const uint2*)&vrow[((cb + 6) ^ l31) * 4];

            oacc = __builtin_amdgcn_mfma_f32_32x32x16_bf16(fa.v, b0.v, oacc, 0, 0, 0);
            oacc = __builtin_amdgcn_mfma_f32_32x32x16_bf16(fb.v, b1.v, oacc, 0, 0, 0);
        }
        __builtin_amdgcn_s_setprio(0);
    }

    // partial[i][jg*32 + c] (bf16): c<30 = raw pre-Wo H, c==31 = rowsum
#pragma unroll
    for (int r = 0; r < 16; ++r) {
        int ir = (r & 3) + 8 * (r >> 2) + 4 * h2 + i0w;
        partial[(size_t)ir * (JGC * 32) + jg * 32 + l31] = f2bf(oacc[r]);
    }
}

// ---------------------------------------------------------------------------
// Kernel C: epilogue v4 (wave-per-row, zero __syncthreads), bf16 partial in.
// P1: lane reads 8 bf16 (stride 64 over the 512-wide row), fold ^32.
// ---------------------------------------------------------------------------
__global__ __launch_bounds__(256) void dv_epilogue_kernel(
    const ushort* __restrict__ partial,
    const float* __restrict__ bo,
    const float* __restrict__ ln_g, const float* __restrict__ ln_b,
    const float* __restrict__ W1, const float* __restrict__ b1,
    const float* __restrict__ W2e, const float* __restrict__ b2e,
    float* __restrict__ out)
{
    __shared__ float shf[4][FFD];    // per-wave private silu slice

    const int tid  = threadIdx.x;
    const int wv   = tid >> 6;
    const int lane = tid & 63;
    const int row  = blockIdx.x * 4 + wv;
    const int c    = lane & 31;
    const int half = lane >> 5;
    const bool a30 = c < 30;
    const int  c30 = a30 ? c : 0;

    // P1: row's 512 bf16 partials; lane reads 8 (stride 64), fold lane^32.
    float s8 = 0.f;
    {
        const ushort* pp = partial + (size_t)row * (JGC * 32) + lane;
#pragma unroll
        for (int q = 0; q < 8; ++q) s8 += bf2f(pp[q * 64]);
    }
    float sv = s8 + __shfl_xor(s8, 32, 64);   // col sums, dup in both halves

    float rsum = __shfl(sv, 31, 32);          // col 31 = rowsum
    float inv  = __builtin_amdgcn_rcpf(rsum + 1e-8f);
    float Hl   = a30 ? fmaf(sv, inv, bo[c30]) : 0.f;

    // LayerNorm in-register (width-32; lanes with c>=30 contribute 0)
    float x = Hl;
#pragma unroll
    for (int m = 1; m < 32; m <<= 1) x += __shfl_xor(x, m, 32);
    float mu = x * (1.0f / D_OUT);
    float d  = a30 ? (Hl - mu) : 0.f;
    float v2 = d * d;
#pragma unroll
    for (int m = 1; m < 32; m <<= 1) v2 += __shfl_xor(v2, m, 32);
    float rs = rsqrtf(v2 * (1.0f / D_OUT) + 1e-5f);
    float Hn = fmaf(d * rs, ln_g[c30], ln_b[c30]);  // valid where a30

    // FFN1 + SiLU: lane owns f = lane and f = lane + 64 (coalesced W1 rows)
    float acc0 = b1[lane], acc1 = b1[lane + 64];
#pragma unroll
    for (int o = 0; o < D_OUT; ++o) {
        float ho = rdlane(Hn, o);             // lane o < 30 holds Hn[o]
        acc0 = fmaf(ho, W1[o * FFD + lane], acc0);
        acc1 = fmaf(ho, W1[o * FFD + lane + 64], acc1);
    }
    const float L2E = 1.4426950408889634f;
    shf[wv][lane] =
        acc0 * __builtin_amdgcn_rcpf(1.0f + __builtin_amdgcn_exp2f(-acc0 * L2E));
    shf[wv][lane + 64] =
        acc1 * __builtin_amdgcn_rcpf(1.0f + __builtin_amdgcn_exp2f(-acc1 * L2E));
    // same-wave ds_write -> ds_read: ordered by lgkmcnt, no barrier needed

    // FFN2e: half-wave h covers f in [h*64, h*64+64); o = c30 per lane.
    float acc = 0.f;
    {
        const float* hbase = &shf[wv][half * 64];
#pragma unroll
        for (int k = 0; k < 16; ++k) {
            float4 hv = *(const float4*)&hbase[k * 4];
            const int f0 = half * 64 + k * 4;
            acc = fmaf(hv.x, W2e[(f0    ) * D_OUT + c30], acc);
            acc = fmaf(hv.y, W2e[(f0 + 1) * D_OUT + c30], acc);
            acc = fmaf(hv.z, W2e[(f0 + 2) * D_OUT + c30], acc);
            acc = fmaf(hv.w, W2e[(f0 + 3) * D_OUT + c30], acc);
        }
    }
    float val = acc + __shfl_xor(acc, 32, 64) + b2e[c30];

    if (lane < 32 && a30)
        out[(size_t)row * ZC + c] = val;

    float kep = (a30 && half == 0) ? val * val : 0.f;
#pragma unroll
    for (int m = 1; m < 32; m <<= 1) kep += __shfl_xor(kep, m, 32);
    if (lane == 0) {
        float* op = out + (size_t)row * ZC;
        op[30] = 0.f; op[31] = 0.f; op[32] = 0.f;
        op[33] = kep * (0.5f / D_OUT);
    }
}

// ---------------------------------------------------------------------------
extern "C" void kernel_launch(void* const* d_in, const int* in_sizes, int n_in,
                              void* d_out, int out_size, void* d_ws, size_t ws_size,
                              hipStream_t stream)
{
    const float* Z  = (const float*)d_in[1];
    const float* Wq = (const float*)d_in[2];
    const float* bq = (const float*)d_in[3];
    const float* Wk = (const float*)d_in[4];
    const float* bk = (const float*)d_in[5];
    const float* Wv = (const float*)d_in[6];
    const float* bv = (const float*)d_in[7];
    const float* Wo = (const float*)d_in[8];
    const float* bo = (const float*)d_in[9];
    const float* lg = (const float*)d_in[10];
    const float* lb = (const float*)d_in[11];
    const float* W1 = (const float*)d_in[12];
    const float* b1 = (const float*)d_in[13];
    const float* W2 = (const float*)d_in[14];
    const float* b2 = (const float*)d_in[15];
    const float* We = (const float*)d_in[16];
    const float* be = (const float*)d_in[17];
    float* out = (float*)d_out;

    ushort* Qb   = (ushort*)d_ws;                 // N*32 bf16
    ushort* Kb   = Qb + (size_t)N * HID;          // N*32 bf16
    ushort* VWot = Kb + (size_t)N * HID;          // [32][N] bf16 (V@Wo)^T
    ushort* KA   = VWot + (size_t)N * HID;        // [2][N][8] bf16
    ushort* QB   = KA + (size_t)N * 16;           // [2][N][8] bf16
    float*  W2e  = (float*)(QB + (size_t)N * 16); // [128][30]
    float*  b2e  = W2e + FFD * D_OUT;             // [30] (+pad)
    ushort* partial = (ushort*)(b2e + 32);        // [N][JGC*32] bf16

    int nch = N / (JGC * 128);

    hipLaunchKernelGGL(dv_qkv_kernel, dim3((N * HID) / 256), dim3(256), 0, stream,
                       Z, Wq, bq, Wk, bk, Wv, bv, Wo, W2, We, b2, be,
                       Qb, Kb, VWot, KA, QB, W2e, b2e);
    hipLaunchKernelGGL(dv_attn_kernel, dim3(64 * JGC), dim3(256), 0, stream,
                       Qb, Kb, VWot, KA, QB, partial, nch);
    hipLaunchKernelGGL(dv_epilogue_kernel, dim3(N / 4), dim3(256), 0, stream,
                       partial, bo, lg, lb, W1, b1, W2e, b2e, out);
}

// Round 20
// 55.874 us; speedup vs baseline: 1.1531x; 1.0142x over previous
//
#include <hip/hip_runtime.h>
#include <hip/hip_bf16.h>

#define N      8192
#define D_IN   30
#define HID    32
#define D_OUT  30
#define FFD    128
#define ZC     34
#define JGC    16     // j-split groups
#define NCH    4      // chunks per jg (compile-time -> full unroll)

typedef __attribute__((ext_vector_type(8))) short short8;
typedef __attribute__((ext_vector_type(16))) float f32x16;

static __device__ __forceinline__ ushort f2bf(float x) {
    uint32_t u = __float_as_uint(x);
    uint32_t r = (u + 0x7fffu + ((u >> 16) & 1u)) >> 16;   // RTNE
    return (ushort)r;
}
static __device__ __forceinline__ float bf2f(ushort u) {
    return __uint_as_float(((uint32_t)u) << 16);
}
static __device__ __forceinline__ float rdlane(float v, int l) {
    return __uint_as_float(__builtin_amdgcn_readlane(__float_as_uint(v), l));
}

// ---------------------------------------------------------------------------
// Kernel A (R14-identical): QKV -> bf16; VWo^T (row30=0,row31=1 -> PV col31
// = rowsum); negated split-bf16 gate tables (gate MFMA = +D); W2e = W2@We,
// b2e = b2@We + be.
// ---------------------------------------------------------------------------
__global__ __launch_bounds__(256) void dv_qkv_kernel(
    const float* __restrict__ Z,
    const float* __restrict__ Wq, const float* __restrict__ bq,
    const float* __restrict__ Wk, const float* __restrict__ bk,
    const float* __restrict__ Wv, const float* __restrict__ bv,
    const float* __restrict__ Wo,
    const float* __restrict__ W2, const float* __restrict__ We,
    const float* __restrict__ b2, const float* __restrict__ be,
    ushort* __restrict__ Qb, ushort* __restrict__ Kb,
    ushort* __restrict__ VWot, ushort* __restrict__ KA,
    ushort* __restrict__ QB, float* __restrict__ W2e, float* __restrict__ b2e)
{
    __shared__ ushort sv[8][33];
    const int t = blockIdx.x * 256 + threadIdx.x;
    const int i = t >> 5;
    const int h = t & 31;
    const float* z = Z + (size_t)i * ZC;

    float q = bq[h], k = bk[h], v = bv[h];
#pragma unroll
    for (int d = 0; d < D_IN; ++d) {
        float zf = z[d];
        q = fmaf(zf, Wq[d * HID + h], q);
        k = fmaf(zf, Wk[d * HID + h], k);
        v = fmaf(zf, Wv[d * HID + h], v);
    }
    const float QS = 0.17677669529663687f * 1.4426950408889634f; // log2e/sqrt(32)
    Qb[(size_t)i * HID + h] = f2bf(q * QS);
    Kb[(size_t)i * HID + h] = f2bf(k);
    sv[threadIdx.x >> 5][h] = f2bf(v);

    if (h == 0) {
        float p0 = z[D_IN], p1 = z[D_IN + 1], p2 = z[D_IN + 2];
        const float C2 = 1.4426950408889634f / 0.18f;   // log2e/(2*sigma^2)
        const float SC = sqrtf(2.0f * C2);
        float px = p0 * SC, py = p1 * SC, pz = p2 * SC;
        float w  = -C2 * (p0 * p0 + p1 * p1 + p2 * p2);
        ushort phx = f2bf(px), phy = f2bf(py), phz = f2bf(pz);
        ushort plx = f2bf(px - bf2f(phx));
        ushort ply = f2bf(py - bf2f(phy));
        ushort plz = f2bf(pz - bf2f(phz));
        ushort wh  = f2bf(w);
        ushort wl  = f2bf(w - bf2f(wh));
        // negate j-side (KA) => MFMA result = +D
        ushort nhx = phx ^ 0x8000, nhy = phy ^ 0x8000, nhz = phz ^ 0x8000;
        ushort nlx = plx ^ 0x8000, nly = ply ^ 0x8000, nlz = plz ^ 0x8000;
        ushort nwh = wh ^ 0x8000,  nwl = wl ^ 0x8000;
        const ushort one = 0x3F80, none = 0xBF80;
        ushort ka0[8] = {nwh, nwl, none, none, nhx, nhy, nhz, nhx};
        ushort ka1[8] = {nhy, nhz, nlx, nly, nlz, nlx, nly, nlz};
        ushort qb0[8] = {one, one, wh, wl, phx, phy, phz, plx};
        ushort qb1[8] = {ply, plz, phx, phy, phz, plx, ply, plz};
        *(uint4*)&KA[(size_t)i * 8]       = *(uint4*)ka0;
        *(uint4*)&KA[((size_t)N + i) * 8] = *(uint4*)ka1;
        *(uint4*)&QB[(size_t)i * 8]       = *(uint4*)qb0;
        *(uint4*)&QB[((size_t)N + i) * 8] = *(uint4*)qb1;
    }

    // W2e = W2 @ We  (+ b2e) over the first 15 blocks
    if (blockIdx.x < 15) {
        int idx = blockIdx.x * 256 + threadIdx.x;      // 0..3839
        int f = idx / 30, o = idx - f * 30;
        float acc = 0.f;
#pragma unroll
        for (int d = 0; d < D_OUT; ++d)
            acc = fmaf(W2[f * D_OUT + d], We[d * D_OUT + o], acc);
        W2e[idx] = acc;
        if (idx < D_OUT) {
            float a2 = be[idx];
#pragma unroll
            for (int d = 0; d < D_OUT; ++d)
                a2 = fmaf(b2[d], We[d * D_OUT + idx], a2);
            b2e[idx] = a2;
        }
    }

    __syncthreads();
    // VWo^T: row c (0..29) = (V@Wo) col c; row 30 = 0; row 31 = 1.0
    const int io = threadIdx.x >> 5, c = threadIdx.x & 31;
    const int ii = blockIdx.x * 8 + io;
    float val;
    if (c < 30) {
        float acc = 0.f;
#pragma unroll
        for (int hh = 0; hh < HID; ++hh)
            acc = fmaf(bf2f(sv[io][hh]), Wo[hh * D_OUT + c], acc);
        val = acc;
    } else {
        val = (c == 31) ? 1.0f : 0.f;
    }
    VWot[(size_t)c * N + ii] = f2bf(val);
}

// ---------------------------------------------------------------------------
// Kernel B: R19 attention (LDS staging, reg prefetch, bounded gate, bf16
// partial, setprio) with COMPILE-TIME chunk count (NCH=4) -> the chunk loop
// fully unrolls: prefetch addresses strength-reduced, deeper scheduling
// window across barrier segments, zero loop overhead.
// ---------------------------------------------------------------------------
__global__ __launch_bounds__(256, 2) void dv_attn_kernel(
    const ushort* __restrict__ Qb, const ushort* __restrict__ Kb,
    const ushort* __restrict__ VWot, const ushort* __restrict__ KA,
    const ushort* __restrict__ QB, ushort* __restrict__ partial)
{
    __shared__ ushort lK[128 * 32];    // K tile, 16B-chunk rot swizzle
    __shared__ ushort lV[32 * 128];    // VWo^T tile, 8B-chunk XOR swizzle
    __shared__ ushort lKA[2][128 * 8]; // gate A-side aug

    const int tid  = threadIdx.x;
    const int lane = tid & 63;
    const int wv   = tid >> 6;
    const int h2   = lane >> 5;
    const int l31  = lane & 31;
    const int rb   = blockIdx.x & 63;
    const int jg   = blockIdx.x >> 6;
    const int i0w  = rb * 128 + wv * 32;

    const ushort* qp = Qb + (size_t)(i0w + l31) * HID + h2 * 8;
    const short8 qf0 = *(const short8*)qp;
    const short8 qf1 = *(const short8*)(qp + 16);
    const short8 qaug = *(const short8*)&QB[((size_t)h2 * N + i0w + l31) * 8];

    f32x16 zacc, oacc;
#pragma unroll
    for (int r = 0; r < 16; ++r) { zacc[r] = 0.f; oacc[r] = 0.f; }

    const int cA0 = (h2 + (l31 >> 1)) & 3;
    const int cA1 = (cA0 + 2) & 3;

    // staging indices (fixed per thread)
    const int kjr0 = tid >> 2,          kcc0 = tid & 3;
    const int kjr1 = (tid + 256) >> 2,  kcc1 = (tid + 256) & 3;
    const int kc20 = (kcc0 + (kjr0 >> 1)) & 3;
    const int kc21 = (kcc1 + (kjr1 >> 1)) & 3;
    const int vhh[4] = { tid >> 5, (tid + 256) >> 5, (tid + 512) >> 5, (tid + 768) >> 5 };
    const int vcx = tid & 31;
    const int ahalf = tid >> 7, ajj = tid & 127;

    uint4 kreg[2];
    uint2 vreg[4];
    uint4 kareg;

    // prologue: load chunk 0
    {
        const int j0 = (jg * NCH) << 7;
        kreg[0] = *(const uint4*)&Kb[(size_t)(j0 + kjr0) * HID + kcc0 * 8];
        kreg[1] = *(const uint4*)&Kb[(size_t)(j0 + kjr1) * HID + kcc1 * 8];
#pragma unroll
        for (int r2 = 0; r2 < 4; ++r2)
            vreg[r2] = *(const uint2*)&VWot[(size_t)vhh[r2] * N + j0 + vcx * 4];
        kareg = *(const uint4*)&KA[((size_t)ahalf * N + j0 + ajj) * 8];
    }

#pragma unroll
    for (int ch = 0; ch < NCH; ++ch) {
        __syncthreads();   // previous compute done; LDS free
        *(uint4*)&lK[kjr0 * 32 + kc20 * 8] = kreg[0];
        *(uint4*)&lK[kjr1 * 32 + kc21 * 8] = kreg[1];
#pragma unroll
        for (int r2 = 0; r2 < 4; ++r2)
            *(uint2*)&lV[vhh[r2] * 128 + (vcx ^ vhh[r2]) * 4] = vreg[r2];
        *(uint4*)&lKA[ahalf][ajj * 8] = kareg;
        __syncthreads();   // LDS ready

        // issue next chunk's global loads (land under this chunk's compute)
        if (ch + 1 < NCH) {
            const int j1 = (jg * NCH + ch + 1) << 7;
            kreg[0] = *(const uint4*)&Kb[(size_t)(j1 + kjr0) * HID + kcc0 * 8];
            kreg[1] = *(const uint4*)&Kb[(size_t)(j1 + kjr1) * HID + kcc1 * 8];
#pragma unroll
            for (int r2 = 0; r2 < 4; ++r2)
                vreg[r2] = *(const uint2*)&VWot[(size_t)vhh[r2] * N + j1 + vcx * 4];
            kareg = *(const uint4*)&KA[((size_t)ahalf * N + j1 + ajj) * 8];
        }

        __builtin_amdgcn_s_setprio(1);
#pragma unroll
        for (int t32 = 0; t32 < 4; ++t32) {
            const ushort* krow = &lK[(t32 * 32 + l31) * 32];
            short8 kf0 = *(const short8*)&krow[cA0 * 8];
            short8 kf1 = *(const short8*)&krow[cA1 * 8];
            f32x16 s = __builtin_amdgcn_mfma_f32_32x32x16_bf16(kf0, qf0, zacc, 0, 0, 0);
            s = __builtin_amdgcn_mfma_f32_32x32x16_bf16(kf1, qf1, s, 0, 0, 0);

            short8 kaug = *(const short8*)&lKA[h2][(t32 * 32 + l31) * 8];
            f32x16 gA = __builtin_amdgcn_mfma_f32_32x32x16_bf16(kaug, qaug, zacc, 0, 0, 0);

            uint32_t pk[8];
#pragma unroll
            for (int p = 0; p < 8; ++p) {
                // a = 2^-D * rcp(1 + 2^-S'); D >= -eps, all factors bounded
                float eg0 = __builtin_amdgcn_exp2f(-gA[2 * p]);
                float es0 = __builtin_amdgcn_exp2f(-s[2 * p]);
                float a0  = eg0 * __builtin_amdgcn_rcpf(1.0f + es0);
                float eg1 = __builtin_amdgcn_exp2f(-gA[2 * p + 1]);
                float es1 = __builtin_amdgcn_exp2f(-s[2 * p + 1]);
                float a1  = eg1 * __builtin_amdgcn_rcpf(1.0f + es1);
                asm("v_cvt_pk_bf16_f32 %0, %1, %2" : "=v"(pk[p]) : "v"(a0), "v"(a1));
            }
            union BV { uint32_t u[4]; short8 v; };
            BV fa, fb;
            fa.u[0] = pk[0]; fa.u[1] = pk[1]; fa.u[2] = pk[2]; fa.u[3] = pk[3];
            fb.u[0] = pk[4]; fb.u[1] = pk[5]; fb.u[2] = pk[6]; fb.u[3] = pk[7];

            const ushort* vrow = &lV[l31 * 128];
            const int cb = t32 * 8 + h2;
            BV b0, b1;
            *(uint2*)&b0.u[0] = *(const uint2*)&vrow[((cb    ) ^ l31) * 4];
            *(uint2*)&b0.u[2] = *(const uint2*)&vrow[((cb + 2) ^ l31) * 4];
            *(uint2*)&b1.u[0] = *(const uint2*)&vrow[((cb + 4) ^ l31) * 4];
            *(uint2*)&b1.u[2] = *(const uint2*)&vrow[((cb + 6) ^ l31) * 4];

            oacc = __builtin_amdgcn_mfma_f32_32x32x16_bf16(fa.v, b0.v, oacc, 0, 0, 0);
            oacc = __builtin_amdgcn_mfma_f32_32x32x16_bf16(fb.v, b1.v, oacc, 0, 0, 0);
        }
        __builtin_amdgcn_s_setprio(0);
    }

    // partial[i][jg*32 + c] (bf16): c<30 = raw pre-Wo H, c==31 = rowsum
#pragma unroll
    for (int r = 0; r < 16; ++r) {
        int ir = (r & 3) + 8 * (r >> 2) + 4 * h2 + i0w;
        partial[(size_t)ir * (JGC * 32) + jg * 32 + l31] = f2bf(oacc[r]);
    }
}

// ---------------------------------------------------------------------------
// Kernel C (R19-identical): epilogue v4 — wave-per-row, zero __syncthreads,
// bf16 partial in.
// ---------------------------------------------------------------------------
__global__ __launch_bounds__(256) void dv_epilogue_kernel(
    const ushort* __restrict__ partial,
    const float* __restrict__ bo,
    const float* __restrict__ ln_g, const float* __restrict__ ln_b,
    const float* __restrict__ W1, const float* __restrict__ b1,
    const float* __restrict__ W2e, const float* __restrict__ b2e,
    float* __restrict__ out)
{
    __shared__ float shf[4][FFD];    // per-wave private silu slice

    const int tid  = threadIdx.x;
    const int wv   = tid >> 6;
    const int lane = tid & 63;
    const int row  = blockIdx.x * 4 + wv;
    const int c    = lane & 31;
    const int half = lane >> 5;
    const bool a30 = c < 30;
    const int  c30 = a30 ? c : 0;

    // P1: row's 512 bf16 partials; lane reads 8 (stride 64), fold lane^32.
    float s8 = 0.f;
    {
        const ushort* pp = partial + (size_t)row * (JGC * 32) + lane;
#pragma unroll
        for (int q = 0; q < 8; ++q) s8 += bf2f(pp[q * 64]);
    }
    float sv = s8 + __shfl_xor(s8, 32, 64);   // col sums, dup in both halves

    float rsum = __shfl(sv, 31, 32);          // col 31 = rowsum
    float inv  = __builtin_amdgcn_rcpf(rsum + 1e-8f);
    float Hl   = a30 ? fmaf(sv, inv, bo[c30]) : 0.f;

    // LayerNorm in-register (width-32; lanes with c>=30 contribute 0)
    float x = Hl;
#pragma unroll
    for (int m = 1; m < 32; m <<= 1) x += __shfl_xor(x, m, 32);
    float mu = x * (1.0f / D_OUT);
    float d  = a30 ? (Hl - mu) : 0.f;
    float v2 = d * d;
#pragma unroll
    for (int m = 1; m < 32; m <<= 1) v2 += __shfl_xor(v2, m, 32);
    float rs = rsqrtf(v2 * (1.0f / D_OUT) + 1e-5f);
    float Hn = fmaf(d * rs, ln_g[c30], ln_b[c30]);  // valid where a30

    // FFN1 + SiLU: lane owns f = lane and f = lane + 64 (coalesced W1 rows)
    float acc0 = b1[lane], acc1 = b1[lane + 64];
#pragma unroll
    for (int o = 0; o < D_OUT; ++o) {
        float ho = rdlane(Hn, o);             // lane o < 30 holds Hn[o]
        acc0 = fmaf(ho, W1[o * FFD + lane], acc0);
        acc1 = fmaf(ho, W1[o * FFD + lane + 64], acc1);
    }
    const float L2E = 1.4426950408889634f;
    shf[wv][lane] =
        acc0 * __builtin_amdgcn_rcpf(1.0f + __builtin_amdgcn_exp2f(-acc0 * L2E));
    shf[wv][lane + 64] =
        acc1 * __builtin_amdgcn_rcpf(1.0f + __builtin_amdgcn_exp2f(-acc1 * L2E));
    // same-wave ds_write -> ds_read: ordered by lgkmcnt, no barrier needed

    // FFN2e: half-wave h covers f in [h*64, h*64+64); o = c30 per lane.
    float acc = 0.f;
    {
        const float* hbase = &shf[wv][half * 64];
#pragma unroll
        for (int k = 0; k < 16; ++k) {
            float4 hv = *(const float4*)&hbase[k * 4];
            const int f0 = half * 64 + k * 4;
            acc = fmaf(hv.x, W2e[(f0    ) * D_OUT + c30], acc);
            acc = fmaf(hv.y, W2e[(f0 + 1) * D_OUT + c30], acc);
            acc = fmaf(hv.z, W2e[(f0 + 2) * D_OUT + c30], acc);
            acc = fmaf(hv.w, W2e[(f0 + 3) * D_OUT + c30], acc);
        }
    }
    float val = acc + __shfl_xor(acc, 32, 64) + b2e[c30];

    if (lane < 32 && a30)
        out[(size_t)row * ZC + c] = val;

    float kep = (a30 && half == 0) ? val * val : 0.f;
#pragma unroll
    for (int m = 1; m < 32; m <<= 1) kep += __shfl_xor(kep, m, 32);
    if (lane == 0) {
        float* op = out + (size_t)row * ZC;
        op[30] = 0.f; op[31] = 0.f; op[32] = 0.f;
        op[33] = kep * (0.5f / D_OUT);
    }
}

// ---------------------------------------------------------------------------
extern "C" void kernel_launch(void* const* d_in, const int* in_sizes, int n_in,
                              void* d_out, int out_size, void* d_ws, size_t ws_size,
                              hipStream_t stream)
{
    const float* Z  = (const float*)d_in[1];
    const float* Wq = (const float*)d_in[2];
    const float* bq = (const float*)d_in[3];
    const float* Wk = (const float*)d_in[4];
    const float* bk = (const float*)d_in[5];
    const float* Wv = (const float*)d_in[6];
    const float* bv = (const float*)d_in[7];
    const float* Wo = (const float*)d_in[8];
    const float* bo = (const float*)d_in[9];
    const float* lg = (const float*)d_in[10];
    const float* lb = (const float*)d_in[11];
    const float* W1 = (const float*)d_in[12];
    const float* b1 = (const float*)d_in[13];
    const float* W2 = (const float*)d_in[14];
    const float* b2 = (const float*)d_in[15];
    const float* We = (const float*)d_in[16];
    const float* be = (const float*)d_in[17];
    float* out = (float*)d_out;

    ushort* Qb   = (ushort*)d_ws;                 // N*32 bf16
    ushort* Kb   = Qb + (size_t)N * HID;          // N*32 bf16
    ushort* VWot = Kb + (size_t)N * HID;          // [32][N] bf16 (V@Wo)^T
    ushort* KA   = VWot + (size_t)N * HID;        // [2][N][8] bf16
    ushort* QB   = KA + (size_t)N * 16;           // [2][N][8] bf16
    float*  W2e  = (float*)(QB + (size_t)N * 16); // [128][30]
    float*  b2e  = W2e + FFD * D_OUT;             // [30] (+pad)
    ushort* partial = (ushort*)(b2e + 32);        // [N][JGC*32] bf16

    hipLaunchKernelGGL(dv_qkv_kernel, dim3((N * HID) / 256), dim3(256), 0, stream,
                       Z, Wq, bq, Wk, bk, Wv, bv, Wo, W2, We, b2, be,
                       Qb, Kb, VWot, KA, QB, W2e, b2e);
    hipLaunchKernelGGL(dv_attn_kernel, dim3(64 * JGC), dim3(256), 0, stream,
                       Qb, Kb, VWot, KA, QB, partial);
    hipLaunchKernelGGL(dv_epilogue_kernel, dim3(N / 4), dim3(256), 0, stream,
                       partial, bo, lg, lb, W1, b1, W2e, b2e, out);
}

// Round 21
// 55.522 us; speedup vs baseline: 1.1604x; 1.0063x over previous
//
#include <hip/hip_runtime.h>
#include <hip/hip_bf16.h>

#define N      8192
#define D_IN   30
#define HID    32
#define D_OUT  30
#define FFD    128
#define ZC     34
#define JGC    16     // j-split groups
#define NCH    4      // chunks per jg (compile-time -> full unroll)

typedef __attribute__((ext_vector_type(8))) short short8;
typedef __attribute__((ext_vector_type(16))) float f32x16;

static __device__ __forceinline__ ushort f2bf(float x) {
    uint32_t u = __float_as_uint(x);
    uint32_t r = (u + 0x7fffu + ((u >> 16) & 1u)) >> 16;   // RTNE
    return (ushort)r;
}
static __device__ __forceinline__ float bf2f(ushort u) {
    return __uint_as_float(((uint32_t)u) << 16);
}
static __device__ __forceinline__ float rdlane(float v, int l) {
    return __uint_as_float(__builtin_amdgcn_readlane(__float_as_uint(v), l));
}

// ---------------------------------------------------------------------------
// Kernel A (R14-identical): QKV -> bf16; VWo^T (row30=0,row31=1 -> PV col31
// = rowsum); negated split-bf16 gate tables (gate MFMA = +D); W2e = W2@We,
// b2e = b2@We + be.
// ---------------------------------------------------------------------------
__global__ __launch_bounds__(256) void dv_qkv_kernel(
    const float* __restrict__ Z,
    const float* __restrict__ Wq, const float* __restrict__ bq,
    const float* __restrict__ Wk, const float* __restrict__ bk,
    const float* __restrict__ Wv, const float* __restrict__ bv,
    const float* __restrict__ Wo,
    const float* __restrict__ W2, const float* __restrict__ We,
    const float* __restrict__ b2, const float* __restrict__ be,
    ushort* __restrict__ Qb, ushort* __restrict__ Kb,
    ushort* __restrict__ VWot, ushort* __restrict__ KA,
    ushort* __restrict__ QB, float* __restrict__ W2e, float* __restrict__ b2e)
{
    __shared__ ushort sv[8][33];
    const int t = blockIdx.x * 256 + threadIdx.x;
    const int i = t >> 5;
    const int h = t & 31;
    const float* z = Z + (size_t)i * ZC;

    float q = bq[h], k = bk[h], v = bv[h];
#pragma unroll
    for (int d = 0; d < D_IN; ++d) {
        float zf = z[d];
        q = fmaf(zf, Wq[d * HID + h], q);
        k = fmaf(zf, Wk[d * HID + h], k);
        v = fmaf(zf, Wv[d * HID + h], v);
    }
    const float QS = 0.17677669529663687f * 1.4426950408889634f; // log2e/sqrt(32)
    Qb[(size_t)i * HID + h] = f2bf(q * QS);
    Kb[(size_t)i * HID + h] = f2bf(k);
    sv[threadIdx.x >> 5][h] = f2bf(v);

    if (h == 0) {
        float p0 = z[D_IN], p1 = z[D_IN + 1], p2 = z[D_IN + 2];
        const float C2 = 1.4426950408889634f / 0.18f;   // log2e/(2*sigma^2)
        const float SC = sqrtf(2.0f * C2);
        float px = p0 * SC, py = p1 * SC, pz = p2 * SC;
        float w  = -C2 * (p0 * p0 + p1 * p1 + p2 * p2);
        ushort phx = f2bf(px), phy = f2bf(py), phz = f2bf(pz);
        ushort plx = f2bf(px - bf2f(phx));
        ushort ply = f2bf(py - bf2f(phy));
        ushort plz = f2bf(pz - bf2f(phz));
        ushort wh  = f2bf(w);
        ushort wl  = f2bf(w - bf2f(wh));
        // negate j-side (KA) => MFMA result = +D
        ushort nhx = phx ^ 0x8000, nhy = phy ^ 0x8000, nhz = phz ^ 0x8000;
        ushort nlx = plx ^ 0x8000, nly = ply ^ 0x8000, nlz = plz ^ 0x8000;
        ushort nwh = wh ^ 0x8000,  nwl = wl ^ 0x8000;
        const ushort one = 0x3F80, none = 0xBF80;
        ushort ka0[8] = {nwh, nwl, none, none, nhx, nhy, nhz, nhx};
        ushort ka1[8] = {nhy, nhz, nlx, nly, nlz, nlx, nly, nlz};
        ushort qb0[8] = {one, one, wh, wl, phx, phy, phz, plx};
        ushort qb1[8] = {ply, plz, phx, phy, phz, plx, ply, plz};
        *(uint4*)&KA[(size_t)i * 8]       = *(uint4*)ka0;
        *(uint4*)&KA[((size_t)N + i) * 8] = *(uint4*)ka1;
        *(uint4*)&QB[(size_t)i * 8]       = *(uint4*)qb0;
        *(uint4*)&QB[((size_t)N + i) * 8] = *(uint4*)qb1;
    }

    // W2e = W2 @ We  (+ b2e) over the first 15 blocks
    if (blockIdx.x < 15) {
        int idx = blockIdx.x * 256 + threadIdx.x;      // 0..3839
        int f = idx / 30, o = idx - f * 30;
        float acc = 0.f;
#pragma unroll
        for (int d = 0; d < D_OUT; ++d)
            acc = fmaf(W2[f * D_OUT + d], We[d * D_OUT + o], acc);
        W2e[idx] = acc;
        if (idx < D_OUT) {
            float a2 = be[idx];
#pragma unroll
            for (int d = 0; d < D_OUT; ++d)
                a2 = fmaf(b2[d], We[d * D_OUT + idx], a2);
            b2e[idx] = a2;
        }
    }

    __syncthreads();
    // VWo^T: row c (0..29) = (V@Wo) col c; row 30 = 0; row 31 = 1.0
    const int io = threadIdx.x >> 5, c = threadIdx.x & 31;
    const int ii = blockIdx.x * 8 + io;
    float val;
    if (c < 30) {
        float acc = 0.f;
#pragma unroll
        for (int hh = 0; hh < HID; ++hh)
            acc = fmaf(bf2f(sv[io][hh]), Wo[hh * D_OUT + c], acc);
        val = acc;
    } else {
        val = (c == 31) ? 1.0f : 0.f;
    }
    VWot[(size_t)c * N + ii] = f2bf(val);
}

// ---------------------------------------------------------------------------
// Kernel B: R20 attention with DOUBLE-BUFFERED LDS -> one barrier per chunk
// (was two). Iteration ch: issue ch+1 loads -> barrier -> compute buf[ch&1]
// -> ds_write regs into buf[(ch+1)&1]. Barrier proof: barrier(ch) ensures
// buf[ch&1] writes complete AND all waves done reading buf[(ch-1)&1] before
// its overwrite in iteration ch's tail. LDS 41KB -> still 2 blocks/CU.
// ---------------------------------------------------------------------------
__global__ __launch_bounds__(256, 2) void dv_attn_kernel(
    const ushort* __restrict__ Qb, const ushort* __restrict__ Kb,
    const ushort* __restrict__ VWot, const ushort* __restrict__ KA,
    const ushort* __restrict__ QB, ushort* __restrict__ partial)
{
    __shared__ ushort lK[2][128 * 32];    // K tiles, 16B-chunk rot swizzle
    __shared__ ushort lV[2][32 * 128];    // VWo^T tiles, 8B-chunk XOR swizzle
    __shared__ ushort lKA[2][2][128 * 8]; // gate A-side aug

    const int tid  = threadIdx.x;
    const int lane = tid & 63;
    const int wv   = tid >> 6;
    const int h2   = lane >> 5;
    const int l31  = lane & 31;
    const int rb   = blockIdx.x & 63;
    const int jg   = blockIdx.x >> 6;
    const int i0w  = rb * 128 + wv * 32;

    const ushort* qp = Qb + (size_t)(i0w + l31) * HID + h2 * 8;
    const short8 qf0 = *(const short8*)qp;
    const short8 qf1 = *(const short8*)(qp + 16);
    const short8 qaug = *(const short8*)&QB[((size_t)h2 * N + i0w + l31) * 8];

    f32x16 zacc, oacc;
#pragma unroll
    for (int r = 0; r < 16; ++r) { zacc[r] = 0.f; oacc[r] = 0.f; }

    const int cA0 = (h2 + (l31 >> 1)) & 3;
    const int cA1 = (cA0 + 2) & 3;

    // staging indices (fixed per thread)
    const int kjr0 = tid >> 2,          kcc0 = tid & 3;
    const int kjr1 = (tid + 256) >> 2,  kcc1 = (tid + 256) & 3;
    const int kc20 = (kcc0 + (kjr0 >> 1)) & 3;
    const int kc21 = (kcc1 + (kjr1 >> 1)) & 3;
    const int vhh[4] = { tid >> 5, (tid + 256) >> 5, (tid + 512) >> 5, (tid + 768) >> 5 };
    const int vcx = tid & 31;
    const int ahalf = tid >> 7, ajj = tid & 127;

    uint4 kreg[2];
    uint2 vreg[4];
    uint4 kareg;

    auto LOADC = [&](int c) {
        const int j0 = (jg * NCH + c) << 7;
        kreg[0] = *(const uint4*)&Kb[(size_t)(j0 + kjr0) * HID + kcc0 * 8];
        kreg[1] = *(const uint4*)&Kb[(size_t)(j0 + kjr1) * HID + kcc1 * 8];
#pragma unroll
        for (int r2 = 0; r2 < 4; ++r2)
            vreg[r2] = *(const uint2*)&VWot[(size_t)vhh[r2] * N + j0 + vcx * 4];
        kareg = *(const uint4*)&KA[((size_t)ahalf * N + j0 + ajj) * 8];
    };
    auto WRITEC = [&](int b) {
        *(uint4*)&lK[b][kjr0 * 32 + kc20 * 8] = kreg[0];
        *(uint4*)&lK[b][kjr1 * 32 + kc21 * 8] = kreg[1];
#pragma unroll
        for (int r2 = 0; r2 < 4; ++r2)
            *(uint2*)&lV[b][vhh[r2] * 128 + (vcx ^ vhh[r2]) * 4] = vreg[r2];
        *(uint4*)&lKA[b][ahalf][ajj * 8] = kareg;
    };

    // prologue: chunk 0 -> buf 0
    LOADC(0);
    WRITEC(0);

#pragma unroll
    for (int ch = 0; ch < NCH; ++ch) {
        const int cur = ch & 1;
        if (ch + 1 < NCH) LOADC(ch + 1);   // issue early; lands under compute
        __syncthreads();                    // buf[cur] ready; prev reads done

        __builtin_amdgcn_s_setprio(1);
#pragma unroll
        for (int t32 = 0; t32 < 4; ++t32) {
            const ushort* krow = &lK[cur][(t32 * 32 + l31) * 32];
            short8 kf0 = *(const short8*)&krow[cA0 * 8];
            short8 kf1 = *(const short8*)&krow[cA1 * 8];
            f32x16 s = __builtin_amdgcn_mfma_f32_32x32x16_bf16(kf0, qf0, zacc, 0, 0, 0);
            s = __builtin_amdgcn_mfma_f32_32x32x16_bf16(kf1, qf1, s, 0, 0, 0);

            short8 kaug = *(const short8*)&lKA[cur][h2][(t32 * 32 + l31) * 8];
            f32x16 gA = __builtin_amdgcn_mfma_f32_32x32x16_bf16(kaug, qaug, zacc, 0, 0, 0);

            uint32_t pk[8];
#pragma unroll
            for (int p = 0; p < 8; ++p) {
                // a = 2^-D * rcp(1 + 2^-S'); D >= -eps, all factors bounded
                float eg0 = __builtin_amdgcn_exp2f(-gA[2 * p]);
                float es0 = __builtin_amdgcn_exp2f(-s[2 * p]);
                float a0  = eg0 * __builtin_amdgcn_rcpf(1.0f + es0);
                float eg1 = __builtin_amdgcn_exp2f(-gA[2 * p + 1]);
                float es1 = __builtin_amdgcn_exp2f(-s[2 * p + 1]);
                float a1  = eg1 * __builtin_amdgcn_rcpf(1.0f + es1);
                asm("v_cvt_pk_bf16_f32 %0, %1, %2" : "=v"(pk[p]) : "v"(a0), "v"(a1));
            }
            union BV { uint32_t u[4]; short8 v; };
            BV fa, fb;
            fa.u[0] = pk[0]; fa.u[1] = pk[1]; fa.u[2] = pk[2]; fa.u[3] = pk[3];
            fb.u[0] = pk[4]; fb.u[1] = pk[5]; fb.u[2] = pk[6]; fb.u[3] = pk[7];

            const ushort* vrow = &lV[cur][l31 * 128];
            const int cb = t32 * 8 + h2;
            BV b0, b1;
            *(uint2*)&b0.u[0] = *(const uint2*)&vrow[((cb    ) ^ l31) * 4];
            *(uint2*)&b0.u[2] = *(const uint2*)&vrow[((cb + 2) ^ l31) * 4];
            *(uint2*)&b1.u[0] = *(const uint2*)&vrow[((cb + 4) ^ l31) * 4];
            *(uint2*)&b1.u[2] = *(const uint2*)&vrow[((cb + 6) ^ l31) * 4];

            oacc = __builtin_amdgcn_mfma_f32_32x32x16_bf16(fa.v, b0.v, oacc, 0, 0, 0);
            oacc = __builtin_amdgcn_mfma_f32_32x32x16_bf16(fb.v, b1.v, oacc, 0, 0, 0);
        }
        __builtin_amdgcn_s_setprio(0);

        if (ch + 1 < NCH) WRITEC(cur ^ 1);  // fill other buffer; overlaps
    }

    // partial[i][jg*32 + c] (bf16): c<30 = raw pre-Wo H, c==31 = rowsum
#pragma unroll
    for (int r = 0; r < 16; ++r) {
        int ir = (r & 3) + 8 * (r >> 2) + 4 * h2 + i0w;
        partial[(size_t)ir * (JGC * 32) + jg * 32 + l31] = f2bf(oacc[r]);
    }
}

// ---------------------------------------------------------------------------
// Kernel C (R19-identical): epilogue v4 — wave-per-row, zero __syncthreads,
// bf16 partial in.
// ---------------------------------------------------------------------------
__global__ __launch_bounds__(256) void dv_epilogue_kernel(
    const ushort* __restrict__ partial,
    const float* __restrict__ bo,
    const float* __restrict__ ln_g, const float* __restrict__ ln_b,
    const float* __restrict__ W1, const float* __restrict__ b1,
    const float* __restrict__ W2e, const float* __restrict__ b2e,
    float* __restrict__ out)
{
    __shared__ float shf[4][FFD];    // per-wave private silu slice

    const int tid  = threadIdx.x;
    const int wv   = tid >> 6;
    const int lane = tid & 63;
    const int row  = blockIdx.x * 4 + wv;
    const int c    = lane & 31;
    const int half = lane >> 5;
    const bool a30 = c < 30;
    const int  c30 = a30 ? c : 0;

    // P1: row's 512 bf16 partials; lane reads 8 (stride 64), fold lane^32.
    float s8 = 0.f;
    {
        const ushort* pp = partial + (size_t)row * (JGC * 32) + lane;
#pragma unroll
        for (int q = 0; q < 8; ++q) s8 += bf2f(pp[q * 64]);
    }
    float sv = s8 + __shfl_xor(s8, 32, 64);   // col sums, dup in both halves

    float rsum = __shfl(sv, 31, 32);          // col 31 = rowsum
    float inv  = __builtin_amdgcn_rcpf(rsum + 1e-8f);
    float Hl   = a30 ? fmaf(sv, inv, bo[c30]) : 0.f;

    // LayerNorm in-register (width-32; lanes with c>=30 contribute 0)
    float x = Hl;
#pragma unroll
    for (int m = 1; m < 32; m <<= 1) x += __shfl_xor(x, m, 32);
    float mu = x * (1.0f / D_OUT);
    float d  = a30 ? (Hl - mu) : 0.f;
    float v2 = d * d;
#pragma unroll
    for (int m = 1; m < 32; m <<= 1) v2 += __shfl_xor(v2, m, 32);
    float rs = rsqrtf(v2 * (1.0f / D_OUT) + 1e-5f);
    float Hn = fmaf(d * rs, ln_g[c30], ln_b[c30]);  // valid where a30

    // FFN1 + SiLU: lane owns f = lane and f = lane + 64 (coalesced W1 rows)
    float acc0 = b1[lane], acc1 = b1[lane + 64];
#pragma unroll
    for (int o = 0; o < D_OUT; ++o) {
        float ho = rdlane(Hn, o);             // lane o < 30 holds Hn[o]
        acc0 = fmaf(ho, W1[o * FFD + lane], acc0);
        acc1 = fmaf(ho, W1[o * FFD + lane + 64], acc1);
    }
    const float L2E = 1.4426950408889634f;
    shf[wv][lane] =
        acc0 * __builtin_amdgcn_rcpf(1.0f + __builtin_amdgcn_exp2f(-acc0 * L2E));
    shf[wv][lane + 64] =
        acc1 * __builtin_amdgcn_rcpf(1.0f + __builtin_amdgcn_exp2f(-acc1 * L2E));
    // same-wave ds_write -> ds_read: ordered by lgkmcnt, no barrier needed

    // FFN2e: half-wave h covers f in [h*64, h*64+64); o = c30 per lane.
    float acc = 0.f;
    {
        const float* hbase = &shf[wv][half * 64];
#pragma unroll
        for (int k = 0; k < 16; ++k) {
            float4 hv = *(const float4*)&hbase[k * 4];
            const int f0 = half * 64 + k * 4;
            acc = fmaf(hv.x, W2e[(f0    ) * D_OUT + c30], acc);
            acc = fmaf(hv.y, W2e[(f0 + 1) * D_OUT + c30], acc);
            acc = fmaf(hv.z, W2e[(f0 + 2) * D_OUT + c30], acc);
            acc = fmaf(hv.w, W2e[(f0 + 3) * D_OUT + c30], acc);
        }
    }
    float val = acc + __shfl_xor(acc, 32, 64) + b2e[c30];

    if (lane < 32 && a30)
        out[(size_t)row * ZC + c] = val;

    float kep = (a30 && half == 0) ? val * val : 0.f;
#pragma unroll
    for (int m = 1; m < 32; m <<= 1) kep += __shfl_xor(kep, m, 32);
    if (lane == 0) {
        float* op = out + (size_t)row * ZC;
        op[30] = 0.f; op[31] = 0.f; op[32] = 0.f;
        op[33] = kep * (0.5f / D_OUT);
    }
}

// ---------------------------------------------------------------------------
extern "C" void kernel_launch(void* const* d_in, const int* in_sizes, int n_in,
                              void* d_out, int out_size, void* d_ws, size_t ws_size,
                              hipStream_t stream)
{
    const float* Z  = (const float*)d_in[1];
    const float* Wq = (const float*)d_in[2];
    const float* bq = (const float*)d_in[3];
    const float* Wk = (const float*)d_in[4];
    const float* bk = (const float*)d_in[5];
    const float* Wv = (const float*)d_in[6];
    const float* bv = (const float*)d_in[7];
    const float* Wo = (const float*)d_in[8];
    const float* bo = (const float*)d_in[9];
    const float* lg = (const float*)d_in[10];
    const float* lb = (const float*)d_in[11];
    const float* W1 = (const float*)d_in[12];
    const float* b1 = (const float*)d_in[13];
    const float* W2 = (const float*)d_in[14];
    const float* b2 = (const float*)d_in[15];
    const float* We = (const float*)d_in[16];
    const float* be = (const float*)d_in[17];
    float* out = (float*)d_out;

    ushort* Qb   = (ushort*)d_ws;                 // N*32 bf16
    ushort* Kb   = Qb + (size_t)N * HID;          // N*32 bf16
    ushort* VWot = Kb + (size_t)N * HID;          // [32][N] bf16 (V@Wo)^T
    ushort* KA   = VWot + (size_t)N * HID;        // [2][N][8] bf16
    ushort* QB   = KA + (size_t)N * 16;           // [2][N][8] bf16
    float*  W2e  = (float*)(QB + (size_t)N * 16); // [128][30]
    float*  b2e  = W2e + FFD * D_OUT;             // [30] (+pad)
    ushort* partial = (ushort*)(b2e + 32);        // [N][JGC*32] bf16

    hipLaunchKernelGGL(dv_qkv_kernel, dim3((N * HID) / 256), dim3(256), 0, stream,
                       Z, Wq, bq, Wk, bk, Wv, bv, Wo, W2, We, b2, be,
                       Qb, Kb, VWot, KA, QB, W2e, b2e);
    hipLaunchKernelGGL(dv_attn_kernel, dim3(64 * JGC), dim3(256), 0, stream,
                       Qb, Kb, VWot, KA, QB, partial);
    hipLaunchKernelGGL(dv_epilogue_kernel, dim3(N / 4), dim3(256), 0, stream,
                       partial, bo, lg, lb, W1, b1, W2e, b2e, out);
}